// Round 7
// baseline (294.034 us; speedup 1.0000x reference)
//
#include <hip/hip_runtime.h>
#include <hip/hip_fp16.h>
#include <math.h>

// Problem constants (fixed by the reference)
constexpr int   N   = 50000;
constexpr int   E   = 600000;
constexpr int   FIN = 128;
constexpr int   H   = 64;
constexpr int   C   = 40;
constexpr int   K   = 10;
constexpr float CK  = (1.0f - 0.1f) / 10.0f;  // (1-alpha)/K
constexpr float AL  = 0.1f;                   // alpha

typedef float v2f __attribute__((ext_vector_type(2)));

// pack 4 fp32 -> 4 fp8 e4m3 (HW RNE, OCP on gfx950)
__device__ __forceinline__ unsigned pack_fp8x4(float f0, float f1, float f2, float f3) {
    unsigned r = __builtin_amdgcn_cvt_pk_fp8_f32(f0, f1, 0u, false);
    r = __builtin_amdgcn_cvt_pk_fp8_f32(f2, f3, r, true);
    return r;
}

// 4-byte edge record: low 16 = col (u16, N<=65535), high 16 = fp16 weight
__device__ __forceinline__ float ep_w(unsigned v) {
    return __half2float(__ushort_as_half((unsigned short)(v >> 16)));
}
__device__ __forceinline__ unsigned ep_pack(int c, float w) {
    return (unsigned)(unsigned short)c |
           ((unsigned)__half_as_ushort(__float2half_rn(w)) << 16);
}

// 4 fp8 (u32) -> 4 fp32, FMA into s[4]
__device__ __forceinline__ void accum4(float* s, unsigned v, float w) {
    v2f p0 = __builtin_amdgcn_cvt_pk_f32_fp8(v, false);
    v2f p1 = __builtin_amdgcn_cvt_pk_f32_fp8(v, true);
    s[0] = fmaf(w, p0.x, s[0]); s[1] = fmaf(w, p0.y, s[1]);
    s[2] = fmaf(w, p1.x, s[2]); s[3] = fmaf(w, p1.y, s[3]);
}

// ---------------------------------------------------------------------------
// y0 = x @ W1   (N x 128) @ (128 x 64)
// ---------------------------------------------------------------------------
constexpr int G1N  = 64;
constexpr int XPAD = 132;
__global__ __launch_bounds__(256, 2) void k_gemm1(const float* __restrict__ x,
                                                  const float* __restrict__ W1,
                                                  float* __restrict__ y0,
                                                  unsigned char* __restrict__ y0f8) {
    __shared__ float ws[FIN * H];
    __shared__ float xs[G1N * XPAD];
    const float4* W14 = (const float4*)W1;
    const float4* x4  = (const float4*)x;
    int t = threadIdx.x;
    int node0 = blockIdx.x * G1N;
    for (int i = t; i < FIN * H / 4; i += 256) ((float4*)ws)[i] = W14[i];
    for (int p = 0; p < 8; ++p) {
        int idx = p * 256 + t;
        int n   = idx >> 5;
        int kk  = idx & 31;
        int node = node0 + n;
        float4 v = (node < N) ? x4[(size_t)node * (FIN / 4) + kk]
                              : make_float4(0.f, 0.f, 0.f, 0.f);
        *(float4*)(xs + n * XPAD + kk * 4) = v;
    }
    __syncthreads();
    int nb = (t >> 4) * 4;
    int cb = (t & 15) * 4;
    float a00=0,a01=0,a02=0,a03=0, a10=0,a11=0,a12=0,a13=0;
    float a20=0,a21=0,a22=0,a23=0, a30=0,a31=0,a32=0,a33=0;
#pragma unroll 8
    for (int k = 0; k < FIN; ++k) {
        float4 wv = *(const float4*)(ws + k * H + cb);
        float x0 = xs[(nb + 0) * XPAD + k];
        float x1 = xs[(nb + 1) * XPAD + k];
        float x2 = xs[(nb + 2) * XPAD + k];
        float x3 = xs[(nb + 3) * XPAD + k];
        a00 = fmaf(x0, wv.x, a00); a01 = fmaf(x0, wv.y, a01);
        a02 = fmaf(x0, wv.z, a02); a03 = fmaf(x0, wv.w, a03);
        a10 = fmaf(x1, wv.x, a10); a11 = fmaf(x1, wv.y, a11);
        a12 = fmaf(x1, wv.z, a12); a13 = fmaf(x1, wv.w, a13);
        a20 = fmaf(x2, wv.x, a20); a21 = fmaf(x2, wv.y, a21);
        a22 = fmaf(x2, wv.z, a22); a23 = fmaf(x2, wv.w, a23);
        a30 = fmaf(x3, wv.x, a30); a31 = fmaf(x3, wv.y, a31);
        a32 = fmaf(x3, wv.z, a32); a33 = fmaf(x3, wv.w, a33);
    }
    float4 rows[4] = {make_float4(a00,a01,a02,a03), make_float4(a10,a11,a12,a13),
                      make_float4(a20,a21,a22,a23), make_float4(a30,a31,a32,a33)};
#pragma unroll
    for (int i = 0; i < 4; ++i) {
        int node = node0 + nb + i;
        if (node >= N) break;
        float4 r = rows[i];
        *(float4*)(y0 + (size_t)node * H + cb) = r;
        *(unsigned*)(y0f8 + (size_t)node * H + cb) = pack_fp8x4(r.x, r.y, r.z, r.w);
    }
}

// ---------------------------------------------------------------------------
// Per-row edge count, 8-way privatized, 1 edge/thread, 2344 blocks
// (max TLP for the atomic-with-return chain; r5's 586-block/4-edge shape
//  was occupancy-starved at 20%). Return value = edge rank -> rank[].
// ---------------------------------------------------------------------------
__global__ __launch_bounds__(256) void k_count(const int* __restrict__ row,
                                               int* __restrict__ cnt8,
                                               unsigned short* __restrict__ rank) {
    int e = blockIdx.x * 256 + threadIdx.x;
    if (e >= E) return;
    int copy = blockIdx.x & 7;               // == (e>>8)&7
    int r = row[e];
    int old = atomicAdd(&cnt8[(size_t)copy * N + r], 1);
    rank[e] = (unsigned short)old;
}

// ---------------------------------------------------------------------------
// Two-level exclusive scan of PADDED (align-4) degrees -> row_ptr[]
// ---------------------------------------------------------------------------
__global__ __launch_bounds__(1024) void k_scan_blocks(const int* __restrict__ cnt8,
                                                      int* __restrict__ row_ptr,
                                                      int* __restrict__ bsum) {
    __shared__ int s[1024];
    int gid = blockIdx.x * 1024 + threadIdx.x;
    int v = 0;
    if (gid < N) {
#pragma unroll
        for (int c = 0; c < 8; ++c) v += cnt8[(size_t)c * N + gid];
        v = (v + 3) & ~3;   // pad row to multiple of 4 records
    }
    s[threadIdx.x] = v;
    __syncthreads();
    for (int off = 1; off < 1024; off <<= 1) {
        int t = (threadIdx.x >= off) ? s[threadIdx.x - off] : 0;
        __syncthreads();
        s[threadIdx.x] += t;
        __syncthreads();
    }
    if (gid < N) row_ptr[gid] = s[threadIdx.x] - v;  // exclusive
    if (threadIdx.x == 1023) bsum[blockIdx.x] = s[1023];
}

__global__ void k_scan_sums(const int* __restrict__ bsum, int* __restrict__ boff, int nb,
                            int* __restrict__ rowN) {
    int lane = threadIdx.x;
    int orig = (lane < nb) ? bsum[lane] : 0;
    int v = orig;
    for (int off = 1; off < 64; off <<= 1) {
        int t = __shfl_up(v, off, 64);
        if (lane >= off) v += t;
    }
    if (lane < nb) boff[lane] = v - orig;
    if (lane == nb - 1) *rowN = v;   // row_ptr[N] = total padded records
}

// Add block offsets, convert cnt8 copies into per-copy scatter BASES,
// and zero the pad slots (plus the 16 B tail) -> no ep memset needed.
__global__ __launch_bounds__(1024) void k_addoff(int* __restrict__ row_ptr,
                                                 const int* __restrict__ boff,
                                                 int* __restrict__ cnt8,
                                                 unsigned* __restrict__ ep) {
    int gid = blockIdx.x * 1024 + threadIdx.x;
    if (gid < N) {
        int rp = row_ptr[gid] + boff[blockIdx.x];
        row_ptr[gid] = rp;
        int off = rp;
        int real = 0;
#pragma unroll
        for (int c = 0; c < 8; ++c) {
            int t = cnt8[(size_t)c * N + gid];
            cnt8[(size_t)c * N + gid] = off;
            off += t;
            real += t;
        }
        int pd = (real + 3) & ~3;
        for (int j = real; j < pd; ++j) ep[rp + j] = 0u;
    }
    if (gid == 0) {
        int tot = row_ptr[N];           // written by k_scan_sums (prior kernel)
        *(uint4*)(ep + tot) = make_uint4(0u, 0u, 0u, 0u);
    }
}

// ---------------------------------------------------------------------------
// ATOMIC-FREE scatter: p = base[copy][r] + rank[e]; copy = (e>>8)&7
// reproduces k_count's mapping exactly.
// ---------------------------------------------------------------------------
__global__ __launch_bounds__(256) void k_scatter(const int* __restrict__ row,
                                                 const int* __restrict__ col,
                                                 const float* __restrict__ w,
                                                 const unsigned short* __restrict__ rank,
                                                 const int* __restrict__ base8,
                                                 unsigned* __restrict__ ep) {
    int base = blockIdx.x * 1024 + threadIdx.x;
#pragma unroll
    for (int i = 0; i < 4; ++i) {
        int e = base + i * 256;
        if (e < E) {
            int copy = (e >> 8) & 7;
            int r = row[e];
            int p = base8[(size_t)copy * N + r] + rank[e];
            ep[p] = ep_pack(col[e], w[e]);
        }
    }
}

// ---------------------------------------------------------------------------
// Weighted degree from CSR rows (pads add 0) + dinv/dinv2
// ---------------------------------------------------------------------------
__global__ void k_deg_dinv(const unsigned* __restrict__ ep, const int* __restrict__ row_ptr,
                           float* __restrict__ dinv, float* __restrict__ dinv2) {
    int i = blockIdx.x * blockDim.x + threadIdx.x;
    if (i >= N) return;
    float d = 1.0f;   // self-loop weight
    int e0 = row_ptr[i], e1 = row_ptr[i + 1];
    for (int j = e0; j < e1; ++j) d += ep_w(ep[j]);
    float di = rsqrtf(d);
    dinv[i]  = di;
    dinv2[i] = di * di;
}

// ---------------------------------------------------------------------------
// Normalize edge weights in place: w <- dinv[r]*w*dinv[c]  (pads stay 0)
// ---------------------------------------------------------------------------
__global__ __launch_bounds__(256) void k_norm(unsigned* __restrict__ ep,
                                              const int* __restrict__ row_ptr,
                                              const float* __restrict__ dinv) {
    int node = blockIdx.x * 32 + (threadIdx.x >> 3);
    if (node >= N) return;
    int l = threadIdx.x & 7;
    float dr = dinv[node];
    int e0 = row_ptr[node], e1 = row_ptr[node + 1];
    for (int j = e0 + l; j < e1; j += 8) {
        unsigned v = ep[j];
        int c = v & 0xFFFFu;
        ep[j] = ep_pack(c, ep_w(v) * dr * dinv[c]);
    }
}

// ---------------------------------------------------------------------------
// One propagation hop, fp8 h storage, padded 4 B edge records.
// 16 lanes/node (4 nodes/wave), SOFTWARE-PIPELINED GATHERS: batch k's 8
// gathers are in flight while batch k-1 is consumed (records prefetched
// 2 batches ahead) -> 16 gathers in flight/wave instead of 8, at ~same
// VGPR (fp8 gather = 1 VGPR; acch RMW load moved out of the loop).
// The hop is exposed-latency-bound (VALUBusy ~5%, HBM ~2%): per-CU
// in-flight gathers double 256 -> ~512.
// 16 nodes/block. acc fp16 in global. FINAL fuses the MLP epilogue.
// ---------------------------------------------------------------------------
constexpr int HSP = 68;
template <bool WRITE_H, bool ACC_INIT, bool FINAL>
__global__ __launch_bounds__(256) void k_prop(const unsigned* __restrict__ hin,  // N x 16 u32
                                              unsigned* __restrict__ hout,
                                              __half* __restrict__ acch,         // N x H fp16
                                              const float* __restrict__ dinv2,
                                              const int* __restrict__ row_ptr,
                                              const unsigned* __restrict__ ep,
                                              const float4* __restrict__ y04,
                                              const float* __restrict__ b1,
                                              const float* __restrict__ W2,
                                              const float* __restrict__ b2,
                                              float* __restrict__ out) {
    extern __shared__ float smem[];          // FINAL only: w2s | hs | b2s | b1s
    float* w2s = smem;
    float* hs  = smem + H * C;
    float* b2s = hs + 16 * HSP;
    float* b1s = b2s + C;
    int t = threadIdx.x;
    if (FINAL) {
        for (int i = t; i < H * C; i += 256) w2s[i] = W2[i];
        if (t < C) b2s[t] = b2[t];
        if (t < H) b1s[t] = b1[t];
        __syncthreads();
    }
    int lane = t & 63;
    int nib  = (t >> 6) * 4 + (lane >> 4);   // node-in-block 0..15
    int l    = lane & 15;                    // feature quad (4 fp8)
    int node = blockIdx.x * 16 + nib;
    bool nv  = node < N;
    int nodec = nv ? node : N - 1;
    int start = row_ptr[nodec];
    int pdeg  = nv ? (row_ptr[nodec + 1] - start) : 0;   // padded degree (mult of 4)
    int md = pdeg;
#pragma unroll
    for (int off = 16; off <= 32; off <<= 1) md = max(md, __shfl_xor(md, off, 64));

    // hoisted cheap independent loads (1 VGPR each, long-latency insurance)
    size_t base = (size_t)nodec * 16 + l;
    unsigned vself = hin[base];
    float d2       = dinv2[nodec];

    float s[4];
#pragma unroll
    for (int i = 0; i < 4; ++i) s[i] = 0.f;

    const unsigned* rp = ep + start;
    if (md > 0) {
        // records: batch0 (rA), batch1 (rB); gathers for batch0 in flight
        uint4 rA0 = *(const uint4*)rp;
        uint4 rA1 = *(const uint4*)(rp + ((4  < pdeg) ? 4  : 0));
        uint4 rB0 = *(const uint4*)(rp + ((8  < pdeg) ? 8  : 0));
        uint4 rB1 = *(const uint4*)(rp + ((12 < pdeg) ? 12 : 0));
        unsigned g0 = hin[(size_t)(rA0.x & 0xFFFFu) * 16 + l];
        unsigned g1 = hin[(size_t)(rA0.y & 0xFFFFu) * 16 + l];
        unsigned g2 = hin[(size_t)(rA0.z & 0xFFFFu) * 16 + l];
        unsigned g3 = hin[(size_t)(rA0.w & 0xFFFFu) * 16 + l];
        unsigned g4 = hin[(size_t)(rA1.x & 0xFFFFu) * 16 + l];
        unsigned g5 = hin[(size_t)(rA1.y & 0xFFFFu) * 16 + l];
        unsigned g6 = hin[(size_t)(rA1.z & 0xFFFFu) * 16 + l];
        unsigned g7 = hin[(size_t)(rA1.w & 0xFFFFu) * 16 + l];
        for (int b = 0; b < md; b += 8) {
            int n0 = b + 16, n1 = b + 20;
            uint4 rC0 = *(const uint4*)(rp + ((n0 < pdeg) ? n0 : 0));   // records 2 ahead
            uint4 rC1 = *(const uint4*)(rp + ((n1 < pdeg) ? n1 : 0));
            // issue NEXT batch's gathers (from rB) before consuming current
            unsigned h0 = hin[(size_t)(rB0.x & 0xFFFFu) * 16 + l];
            unsigned h1 = hin[(size_t)(rB0.y & 0xFFFFu) * 16 + l];
            unsigned h2 = hin[(size_t)(rB0.z & 0xFFFFu) * 16 + l];
            unsigned h3 = hin[(size_t)(rB0.w & 0xFFFFu) * 16 + l];
            unsigned h4 = hin[(size_t)(rB1.x & 0xFFFFu) * 16 + l];
            unsigned h5 = hin[(size_t)(rB1.y & 0xFFFFu) * 16 + l];
            unsigned h6 = hin[(size_t)(rB1.z & 0xFFFFu) * 16 + l];
            unsigned h7 = hin[(size_t)(rB1.w & 0xFFFFu) * 16 + l];
            // consume current batch (weights from rA; masked slots add 0)
            accum4(s, g0, (b     < pdeg) ? ep_w(rA0.x) : 0.0f);
            accum4(s, g1, (b + 1 < pdeg) ? ep_w(rA0.y) : 0.0f);
            accum4(s, g2, (b + 2 < pdeg) ? ep_w(rA0.z) : 0.0f);
            accum4(s, g3, (b + 3 < pdeg) ? ep_w(rA0.w) : 0.0f);
            accum4(s, g4, (b + 4 < pdeg) ? ep_w(rA1.x) : 0.0f);
            accum4(s, g5, (b + 5 < pdeg) ? ep_w(rA1.y) : 0.0f);
            accum4(s, g6, (b + 6 < pdeg) ? ep_w(rA1.z) : 0.0f);
            accum4(s, g7, (b + 7 < pdeg) ? ep_w(rA1.w) : 0.0f);
            // rotate pipeline
            rA0 = rB0; rA1 = rB1; rB0 = rC0; rB1 = rC1;
            g0 = h0; g1 = h1; g2 = h2; g3 = h3;
            g4 = h4; g5 = h5; g6 = h6; g7 = h7;
        }
    }
    if (nv) {
        accum4(s, vself, d2);                    // self-loop term (order preserved)
        if (WRITE_H) {
            hout[base] = pack_fp8x4(s[0], s[1], s[2], s[3]);
        }
        uint2* ap = (uint2*)(acch + (size_t)nodec * H + l * 4);
        if (FINAL) {
            uint2 old = *ap;
            const unsigned* u = (const unsigned*)&old;
#pragma unroll
            for (int d = 0; d < 2; ++d) {
                float2 f = __half22float2(*(__half2*)&u[d]);
                s[2*d+0] += f.x; s[2*d+1] += f.y;
            }
            float4 ya = y04[(size_t)nodec * (H / 4) + l];
            const float* bp = b1s + l * 4;
            float* hp = hs + nib * HSP + l * 4;
            hp[0] = fmaxf(fmaf(CK, s[0], fmaf(AL, ya.x, bp[0])), 0.f);
            hp[1] = fmaxf(fmaf(CK, s[1], fmaf(AL, ya.y, bp[1])), 0.f);
            hp[2] = fmaxf(fmaf(CK, s[2], fmaf(AL, ya.z, bp[2])), 0.f);
            hp[3] = fmaxf(fmaf(CK, s[3], fmaf(AL, ya.w, bp[3])), 0.f);
        } else {
            if (!ACC_INIT) {
                uint2 old = *ap;
                const unsigned* u = (const unsigned*)&old;
#pragma unroll
                for (int d = 0; d < 2; ++d) {
                    float2 f = __half22float2(*(__half2*)&u[d]);
                    s[2*d+0] += f.x; s[2*d+1] += f.y;
                }
            }
            uint2 nvp;
            unsigned* u = (unsigned*)&nvp;
#pragma unroll
            for (int d = 0; d < 2; ++d) {
                __half2 h = __floats2half2_rn(s[2*d+0], s[2*d+1]);
                u[d] = *(unsigned*)&h;
            }
            *ap = nvp;
        }
    }
    if (FINAL) {
        __syncthreads();
        int node0 = blockIdx.x * 16;
        for (int o = t; o < 16 * C; o += 256) {
            int nl = o / C, c = o % C;
            int n2 = node0 + nl;
            if (n2 >= N) continue;
            float v = b2s[c];
            const float* hr = &hs[nl * HSP];
#pragma unroll
            for (int k = 0; k < H; ++k) v = fmaf(hr[k], w2s[k * C + c], v);
            out[n2 * C + c] = v;
        }
    }
}

// ---------------------------------------------------------------------------
extern "C" void kernel_launch(void* const* d_in, const int* in_sizes, int n_in,
                              void* d_out, int out_size, void* d_ws, size_t ws_size,
                              hipStream_t stream) {
    const float* x  = (const float*)d_in[0];
    const int*   ei = (const int*)d_in[1];
    const float* ew = (const float*)d_in[2];
    const float* W1 = (const float*)d_in[3];
    const float* b1 = (const float*)d_in[4];
    const float* W2 = (const float*)d_in[5];
    const float* b2 = (const float*)d_in[6];
    float* out = (float*)d_out;

    const int* row = ei;
    const int* col = ei + E;

    char* ws = (char*)d_ws;
    size_t off = 0;
    auto alloc = [&](size_t bytes) -> char* {
        char* p = ws + off;
        off = (off + bytes + 1023) & ~(size_t)1023;
        return p;
    };
    constexpr size_t EPAD = (size_t)E + 3 * (size_t)N + 1024;  // padded CSR capacity
    float*          y0   = (float*)alloc((size_t)N * H * 4);
    unsigned char*  y0f8 = (unsigned char*)alloc((size_t)N * H);
    unsigned char*  ha   = (unsigned char*)alloc((size_t)N * H);
    unsigned char*  hb   = (unsigned char*)alloc((size_t)N * H);
    __half*         acch = (__half*)alloc((size_t)N * H * 2);
    int*            cnt8 = (int*)alloc((size_t)8 * N * 4);     // zeroed
    unsigned short* rank = (unsigned short*)alloc((size_t)E * 2);
    float*    dinv   = (float*)   alloc((size_t)N * 4);
    float*    dinv2  = (float*)   alloc((size_t)N * 4);
    int*      row_ptr= (int*)     alloc((size_t)(N + 1) * 4);
    int*      bsum   = (int*)     alloc(64 * 4);
    int*      boff   = (int*)     alloc(64 * 4);
    unsigned* ep     = (unsigned*)alloc(EPAD * 4);             // pads zeroed by k_addoff

    hipMemsetAsync(cnt8, 0, (size_t)8 * N * 4, stream);

    // 1) y0 = x @ W1 (fp32 + fp8)
    k_gemm1<<<(N + G1N - 1) / G1N, 256, 0, stream>>>(x, W1, y0, y0f8);

    // 2) per-row edge counts (XCD-privatized) + per-edge ranks
    k_count<<<(E + 255) / 256, 256, 0, stream>>>(row, cnt8, rank);

    // 3) scan (padded degrees) -> row_ptr; per-copy scatter bases; zero pads
    constexpr int NB = (N + 1023) / 1024;  // 49
    k_scan_blocks<<<NB, 1024, 0, stream>>>(cnt8, row_ptr, bsum);
    k_scan_sums<<<1, 64, 0, stream>>>(bsum, boff, NB, row_ptr + N);
    k_addoff<<<NB, 1024, 0, stream>>>(row_ptr, boff, cnt8, ep);

    // 4) atomic-free scatter, weighted degree + dinv, normalize
    k_scatter<<<(E + 1023) / 1024, 256, 0, stream>>>(row, col, ew, rank, cnt8, ep);
    k_deg_dinv<<<(N + 255) / 256, 256, 0, stream>>>(ep, row_ptr, dinv, dinv2);
    k_norm<<<(N + 31) / 32, 256, 0, stream>>>(ep, row_ptr, dinv);

    // 5) K hops; hop 0 inits acc, hop K-1 fuses the MLP epilogue
    const unsigned* hin = (const unsigned*)y0f8;
    unsigned* bufs[2] = {(unsigned*)ha, (unsigned*)hb};
    const float4* y04 = (const float4*)y0;
    int grid = (N + 15) / 16;
    size_t smemF = (size_t)(H * C + 16 * HSP + C + H) * 4;
    for (int hop = 0; hop < K; ++hop) {
        unsigned* hout = bufs[hop & 1];
        if (hop == 0)
            k_prop<true, true, false><<<grid, 256, 0, stream>>>(hin, hout, acch, dinv2,
                row_ptr, ep, y04, b1, W2, b2, out);
        else if (hop == K - 1)
            k_prop<false, false, true><<<grid, 256, smemF, stream>>>(hin, hout, acch, dinv2,
                row_ptr, ep, y04, b1, W2, b2, out);
        else
            k_prop<true, false, false><<<grid, 256, 0, stream>>>(hin, hout, acch, dinv2,
                row_ptr, ep, y04, b1, W2, b2, out);
        hin = hout;
    }
}

// Round 8
// 291.802 us; speedup vs baseline: 1.0076x; 1.0076x over previous
//
#include <hip/hip_runtime.h>
#include <hip/hip_fp16.h>
#include <math.h>

// Problem constants (fixed by the reference)
constexpr int   N   = 50000;
constexpr int   E   = 600000;
constexpr int   FIN = 128;
constexpr int   H   = 64;
constexpr int   C   = 40;
constexpr int   K   = 10;
constexpr float CK  = (1.0f - 0.1f) / 10.0f;  // (1-alpha)/K
constexpr float AL  = 0.1f;                   // alpha

typedef float v2f __attribute__((ext_vector_type(2)));

// HW_REG_XCC_ID (id=20, offset=0, size=32) -> simm16 = (31<<11)|(0<<6)|20
#define XCC_ID_SIMM ((31 << 11) | 20)

// pack 4 fp32 -> 4 fp8 e4m3 (HW RNE, OCP on gfx950)
__device__ __forceinline__ unsigned pack_fp8x4(float f0, float f1, float f2, float f3) {
    unsigned r = __builtin_amdgcn_cvt_pk_fp8_f32(f0, f1, 0u, false);
    r = __builtin_amdgcn_cvt_pk_fp8_f32(f2, f3, r, true);
    return r;
}

// 4-byte edge record: low 16 = col (u16, N<=65535), high 16 = fp16 weight
__device__ __forceinline__ float ep_w(unsigned v) {
    return __half2float(__ushort_as_half((unsigned short)(v >> 16)));
}
__device__ __forceinline__ unsigned ep_pack(int c, float w) {
    return (unsigned)(unsigned short)c |
           ((unsigned)__half_as_ushort(__float2half_rn(w)) << 16);
}

// 4 fp8 (u32) -> 4 fp32, FMA into s[4]
__device__ __forceinline__ void accum4(float* s, unsigned v, float w) {
    v2f p0 = __builtin_amdgcn_cvt_pk_f32_fp8(v, false);
    v2f p1 = __builtin_amdgcn_cvt_pk_f32_fp8(v, true);
    s[0] = fmaf(w, p0.x, s[0]); s[1] = fmaf(w, p0.y, s[1]);
    s[2] = fmaf(w, p1.x, s[2]); s[3] = fmaf(w, p1.y, s[3]);
}

// ---------------------------------------------------------------------------
// y0 = x @ W1   (N x 128) @ (128 x 64)
// ---------------------------------------------------------------------------
constexpr int G1N  = 64;
constexpr int XPAD = 132;
__global__ __launch_bounds__(256, 2) void k_gemm1(const float* __restrict__ x,
                                                  const float* __restrict__ W1,
                                                  float* __restrict__ y0,
                                                  unsigned char* __restrict__ y0f8) {
    __shared__ float ws[FIN * H];
    __shared__ float xs[G1N * XPAD];
    const float4* W14 = (const float4*)W1;
    const float4* x4  = (const float4*)x;
    int t = threadIdx.x;
    int node0 = blockIdx.x * G1N;
    for (int i = t; i < FIN * H / 4; i += 256) ((float4*)ws)[i] = W14[i];
    for (int p = 0; p < 8; ++p) {
        int idx = p * 256 + t;
        int n   = idx >> 5;
        int kk  = idx & 31;
        int node = node0 + n;
        float4 v = (node < N) ? x4[(size_t)node * (FIN / 4) + kk]
                              : make_float4(0.f, 0.f, 0.f, 0.f);
        *(float4*)(xs + n * XPAD + kk * 4) = v;
    }
    __syncthreads();
    int nb = (t >> 4) * 4;
    int cb = (t & 15) * 4;
    float a00=0,a01=0,a02=0,a03=0, a10=0,a11=0,a12=0,a13=0;
    float a20=0,a21=0,a22=0,a23=0, a30=0,a31=0,a32=0,a33=0;
#pragma unroll 8
    for (int k = 0; k < FIN; ++k) {
        float4 wv = *(const float4*)(ws + k * H + cb);
        float x0 = xs[(nb + 0) * XPAD + k];
        float x1 = xs[(nb + 1) * XPAD + k];
        float x2 = xs[(nb + 2) * XPAD + k];
        float x3 = xs[(nb + 3) * XPAD + k];
        a00 = fmaf(x0, wv.x, a00); a01 = fmaf(x0, wv.y, a01);
        a02 = fmaf(x0, wv.z, a02); a03 = fmaf(x0, wv.w, a03);
        a10 = fmaf(x1, wv.x, a10); a11 = fmaf(x1, wv.y, a11);
        a12 = fmaf(x1, wv.z, a12); a13 = fmaf(x1, wv.w, a13);
        a20 = fmaf(x2, wv.x, a20); a21 = fmaf(x2, wv.y, a21);
        a22 = fmaf(x2, wv.z, a22); a23 = fmaf(x2, wv.w, a23);
        a30 = fmaf(x3, wv.x, a30); a31 = fmaf(x3, wv.y, a31);
        a32 = fmaf(x3, wv.z, a32); a33 = fmaf(x3, wv.w, a33);
    }
    float4 rows[4] = {make_float4(a00,a01,a02,a03), make_float4(a10,a11,a12,a13),
                      make_float4(a20,a21,a22,a23), make_float4(a30,a31,a32,a33)};
#pragma unroll
    for (int i = 0; i < 4; ++i) {
        int node = node0 + nb + i;
        if (node >= N) break;
        float4 r = rows[i];
        *(float4*)(y0 + (size_t)node * H + cb) = r;
        *(unsigned*)(y0f8 + (size_t)node * H + cb) = pack_fp8x4(r.x, r.y, r.z, r.w);
    }
}

// ---------------------------------------------------------------------------
// Per-row edge count, privatized by the REAL XCD id (s_getreg HW_REG_XCC_ID)
// so every atomic is guaranteed XCD-local (blockIdx&7 -> XCD mapping is NOT
// guaranteed; remote-XCD atomics take the slow device-scope path).
// rank[e] packs: copy (bits 13..15) | rank-within-(copy,row) (bits 0..12).
// ---------------------------------------------------------------------------
__global__ __launch_bounds__(256) void k_count(const int* __restrict__ row,
                                               int* __restrict__ cnt8,
                                               unsigned short* __restrict__ rank) {
    int e = blockIdx.x * 256 + threadIdx.x;
    if (e >= E) return;
    unsigned copy = __builtin_amdgcn_s_getreg(XCC_ID_SIMM) & 7u;
    int r = row[e];
    int old = atomicAdd(&cnt8[(size_t)copy * N + r], 1);
    rank[e] = (unsigned short)(old | (copy << 13));
}

// ---------------------------------------------------------------------------
// Two-level exclusive scan of PADDED (align-4) degrees -> row_ptr[]
// ---------------------------------------------------------------------------
__global__ __launch_bounds__(1024) void k_scan_blocks(const int* __restrict__ cnt8,
                                                      int* __restrict__ row_ptr,
                                                      int* __restrict__ bsum) {
    __shared__ int s[1024];
    int gid = blockIdx.x * 1024 + threadIdx.x;
    int v = 0;
    if (gid < N) {
#pragma unroll
        for (int c = 0; c < 8; ++c) v += cnt8[(size_t)c * N + gid];
        v = (v + 3) & ~3;   // pad row to multiple of 4 records
    }
    s[threadIdx.x] = v;
    __syncthreads();
    for (int off = 1; off < 1024; off <<= 1) {
        int t = (threadIdx.x >= off) ? s[threadIdx.x - off] : 0;
        __syncthreads();
        s[threadIdx.x] += t;
        __syncthreads();
    }
    if (gid < N) row_ptr[gid] = s[threadIdx.x] - v;  // exclusive
    if (threadIdx.x == 1023) bsum[blockIdx.x] = s[1023];
}

// Fused (old k_scan_sums + k_addoff): each block computes the bsum prefix
// in its first wave (NB=49 <= 64), adds its offset, converts cnt8 copies
// into per-copy scatter BASES, zeroes row pad slots + the 16 B tail.
constexpr int NB = (N + 1023) / 1024;  // 49
__global__ __launch_bounds__(1024) void k_addoff(int* __restrict__ row_ptr,
                                                 const int* __restrict__ bsum,
                                                 int* __restrict__ cnt8,
                                                 unsigned* __restrict__ ep) {
    __shared__ int sboff;
    __shared__ int stot;
    if (threadIdx.x < 64) {
        int lane = threadIdx.x;
        int orig = (lane < NB) ? bsum[lane] : 0;
        int v = orig;
        for (int off = 1; off < 64; off <<= 1) {
            int t = __shfl_up(v, off, 64);
            if (lane >= off) v += t;
        }
        if (lane == (int)blockIdx.x) sboff = v - orig;   // exclusive prefix
        if (lane == NB - 1)          stot  = v;          // total padded records
    }
    __syncthreads();
    int gid = blockIdx.x * 1024 + threadIdx.x;
    if (gid < N) {
        int rp = row_ptr[gid] + sboff;
        row_ptr[gid] = rp;
        int off = rp;
        int real = 0;
#pragma unroll
        for (int c = 0; c < 8; ++c) {
            int t = cnt8[(size_t)c * N + gid];
            cnt8[(size_t)c * N + gid] = off;
            off += t;
            real += t;
        }
        int pd = (real + 3) & ~3;
        for (int j = real; j < pd; ++j) ep[rp + j] = 0u;
    }
    if (gid == 0) {
        row_ptr[N] = stot;
        *(uint4*)(ep + stot) = make_uint4(0u, 0u, 0u, 0u);
    }
}

// ---------------------------------------------------------------------------
// ATOMIC-FREE scatter: p = base[copy][r] + rank; copy/rank unpacked from
// the rank word written by k_count (copy = real XCD id at count time).
// ---------------------------------------------------------------------------
__global__ __launch_bounds__(256) void k_scatter(const int* __restrict__ row,
                                                 const int* __restrict__ col,
                                                 const float* __restrict__ w,
                                                 const unsigned short* __restrict__ rank,
                                                 const int* __restrict__ base8,
                                                 unsigned* __restrict__ ep) {
    int base = blockIdx.x * 1024 + threadIdx.x;
#pragma unroll
    for (int i = 0; i < 4; ++i) {
        int e = base + i * 256;
        if (e < E) {
            unsigned rk = rank[e];
            int copy = rk >> 13;
            int r = row[e];
            int p = base8[(size_t)copy * N + r] + (rk & 0x1FFF);
            ep[p] = ep_pack(col[e], w[e]);
        }
    }
}

// ---------------------------------------------------------------------------
// Weighted degree from CSR rows (pads add 0) + dinv/dinv2
// ---------------------------------------------------------------------------
__global__ void k_deg_dinv(const unsigned* __restrict__ ep, const int* __restrict__ row_ptr,
                           float* __restrict__ dinv, float* __restrict__ dinv2) {
    int i = blockIdx.x * blockDim.x + threadIdx.x;
    if (i >= N) return;
    float d = 1.0f;   // self-loop weight
    int e0 = row_ptr[i], e1 = row_ptr[i + 1];
    for (int j = e0; j < e1; ++j) d += ep_w(ep[j]);
    float di = rsqrtf(d);
    dinv[i]  = di;
    dinv2[i] = di * di;
}

// ---------------------------------------------------------------------------
// Normalize edge weights in place: w <- dinv[r]*w*dinv[c]  (pads stay 0)
// ---------------------------------------------------------------------------
__global__ __launch_bounds__(256) void k_norm(unsigned* __restrict__ ep,
                                              const int* __restrict__ row_ptr,
                                              const float* __restrict__ dinv) {
    int node = blockIdx.x * 32 + (threadIdx.x >> 3);
    if (node >= N) return;
    int l = threadIdx.x & 7;
    float dr = dinv[node];
    int e0 = row_ptr[node], e1 = row_ptr[node + 1];
    for (int j = e0 + l; j < e1; j += 8) {
        unsigned v = ep[j];
        int c = v & 0xFFFFu;
        ep[j] = ep_pack(c, ep_w(v) * dr * dinv[c]);
    }
}

// ---------------------------------------------------------------------------
// One propagation hop (r6-best version), fp8 h storage, padded records.
// 16 lanes/node (4 nodes/wave), two uint4 records double-prefetched,
// 8 gathers in flight. 16 nodes/block. acc fp16 in global.
// FINAL fuses the MLP epilogue.
// ---------------------------------------------------------------------------
constexpr int HSP = 68;
template <bool WRITE_H, bool ACC_INIT, bool FINAL>
__global__ __launch_bounds__(256) void k_prop(const unsigned* __restrict__ hin,  // N x 16 u32
                                              unsigned* __restrict__ hout,
                                              __half* __restrict__ acch,         // N x H fp16
                                              const float* __restrict__ dinv2,
                                              const int* __restrict__ row_ptr,
                                              const unsigned* __restrict__ ep,
                                              const float4* __restrict__ y04,
                                              const float* __restrict__ b1,
                                              const float* __restrict__ W2,
                                              const float* __restrict__ b2,
                                              float* __restrict__ out) {
    extern __shared__ float smem[];          // FINAL only: w2s | hs | b2s | b1s
    float* w2s = smem;
    float* hs  = smem + H * C;
    float* b2s = hs + 16 * HSP;
    float* b1s = b2s + C;
    int t = threadIdx.x;
    if (FINAL) {
        for (int i = t; i < H * C; i += 256) w2s[i] = W2[i];
        if (t < C) b2s[t] = b2[t];
        if (t < H) b1s[t] = b1[t];
        __syncthreads();
    }
    int lane = t & 63;
    int nib  = (t >> 6) * 4 + (lane >> 4);   // node-in-block 0..15
    int l    = lane & 15;                    // feature quad (4 fp8)
    int node = blockIdx.x * 16 + nib;
    bool nv  = node < N;
    int nodec = nv ? node : N - 1;
    int start = row_ptr[nodec];
    int pdeg  = nv ? (row_ptr[nodec + 1] - start) : 0;   // padded degree (mult of 4)
    int md = pdeg;
#pragma unroll
    for (int off = 16; off <= 32; off <<= 1) md = max(md, __shfl_xor(md, off, 64));

    size_t base = (size_t)nodec * 16 + l;
    unsigned vself = hin[base];
    float d2       = dinv2[nodec];
    uint2* ap = (uint2*)(acch + (size_t)nodec * H + l * 4);
    uint2 old;
    if (nv && (FINAL || !ACC_INIT)) old = *ap;

    float s[4];
#pragma unroll
    for (int i = 0; i < 4; ++i) s[i] = 0.f;

    const unsigned* rp = ep + start;
    uint4 ea = *(const uint4*)rp;                               // slots 0..3
    uint4 eb = *(const uint4*)(rp + ((4 < pdeg) ? 4 : 0));      // slots 4..7
    for (int batch = 0; batch < md; batch += 8) {
        uint4 ca = ea, cb = eb;
        int n0 = batch + 8, n1 = batch + 12;
        ea = *(const uint4*)(rp + ((n0 < pdeg) ? n0 : 0));      // prefetch next step
        eb = *(const uint4*)(rp + ((n1 < pdeg) ? n1 : 0));
        unsigned v0 = hin[(size_t)(ca.x & 0xFFFFu) * 16 + l];
        unsigned v1 = hin[(size_t)(ca.y & 0xFFFFu) * 16 + l];
        unsigned v2 = hin[(size_t)(ca.z & 0xFFFFu) * 16 + l];
        unsigned v3 = hin[(size_t)(ca.w & 0xFFFFu) * 16 + l];
        unsigned v4 = hin[(size_t)(cb.x & 0xFFFFu) * 16 + l];
        unsigned v5 = hin[(size_t)(cb.y & 0xFFFFu) * 16 + l];
        unsigned v6 = hin[(size_t)(cb.z & 0xFFFFu) * 16 + l];
        unsigned v7 = hin[(size_t)(cb.w & 0xFFFFu) * 16 + l];
        accum4(s, v0, (batch     < pdeg) ? ep_w(ca.x) : 0.0f);
        accum4(s, v1, (batch + 1 < pdeg) ? ep_w(ca.y) : 0.0f);
        accum4(s, v2, (batch + 2 < pdeg) ? ep_w(ca.z) : 0.0f);
        accum4(s, v3, (batch + 3 < pdeg) ? ep_w(ca.w) : 0.0f);
        accum4(s, v4, (batch + 4 < pdeg) ? ep_w(cb.x) : 0.0f);
        accum4(s, v5, (batch + 5 < pdeg) ? ep_w(cb.y) : 0.0f);
        accum4(s, v6, (batch + 6 < pdeg) ? ep_w(cb.z) : 0.0f);
        accum4(s, v7, (batch + 7 < pdeg) ? ep_w(cb.w) : 0.0f);
    }
    if (nv) {
        accum4(s, vself, d2);                    // self-loop term (order preserved)
        if (WRITE_H) {
            hout[base] = pack_fp8x4(s[0], s[1], s[2], s[3]);
        }
        if (FINAL) {
            const unsigned* u = (const unsigned*)&old;
#pragma unroll
            for (int d = 0; d < 2; ++d) {
                float2 f = __half22float2(*(__half2*)&u[d]);
                s[2*d+0] += f.x; s[2*d+1] += f.y;
            }
            float4 ya = y04[(size_t)nodec * (H / 4) + l];
            const float* bp = b1s + l * 4;
            float* hp = hs + nib * HSP + l * 4;
            hp[0] = fmaxf(fmaf(CK, s[0], fmaf(AL, ya.x, bp[0])), 0.f);
            hp[1] = fmaxf(fmaf(CK, s[1], fmaf(AL, ya.y, bp[1])), 0.f);
            hp[2] = fmaxf(fmaf(CK, s[2], fmaf(AL, ya.z, bp[2])), 0.f);
            hp[3] = fmaxf(fmaf(CK, s[3], fmaf(AL, ya.w, bp[3])), 0.f);
        } else {
            if (!ACC_INIT) {
                const unsigned* u = (const unsigned*)&old;
#pragma unroll
                for (int d = 0; d < 2; ++d) {
                    float2 f = __half22float2(*(__half2*)&u[d]);
                    s[2*d+0] += f.x; s[2*d+1] += f.y;
                }
            }
            uint2 nvp;
            unsigned* u = (unsigned*)&nvp;
#pragma unroll
            for (int d = 0; d < 2; ++d) {
                __half2 h = __floats2half2_rn(s[2*d+0], s[2*d+1]);
                u[d] = *(unsigned*)&h;
            }
            *ap = nvp;
        }
    }
    if (FINAL) {
        __syncthreads();
        int node0 = blockIdx.x * 16;
        for (int o = t; o < 16 * C; o += 256) {
            int nl = o / C, c = o % C;
            int n2 = node0 + nl;
            if (n2 >= N) continue;
            float v = b2s[c];
            const float* hr = &hs[nl * HSP];
#pragma unroll
            for (int k = 0; k < H; ++k) v = fmaf(hr[k], w2s[k * C + c], v);
            out[n2 * C + c] = v;
        }
    }
}

// ---------------------------------------------------------------------------
extern "C" void kernel_launch(void* const* d_in, const int* in_sizes, int n_in,
                              void* d_out, int out_size, void* d_ws, size_t ws_size,
                              hipStream_t stream) {
    const float* x  = (const float*)d_in[0];
    const int*   ei = (const int*)d_in[1];
    const float* ew = (const float*)d_in[2];
    const float* W1 = (const float*)d_in[3];
    const float* b1 = (const float*)d_in[4];
    const float* W2 = (const float*)d_in[5];
    const float* b2 = (const float*)d_in[6];
    float* out = (float*)d_out;

    const int* row = ei;
    const int* col = ei + E;

    char* ws = (char*)d_ws;
    size_t off = 0;
    auto alloc = [&](size_t bytes) -> char* {
        char* p = ws + off;
        off = (off + bytes + 1023) & ~(size_t)1023;
        return p;
    };
    constexpr size_t EPAD = (size_t)E + 3 * (size_t)N + 1024;  // padded CSR capacity
    float*          y0   = (float*)alloc((size_t)N * H * 4);
    unsigned char*  y0f8 = (unsigned char*)alloc((size_t)N * H);
    unsigned char*  ha   = (unsigned char*)alloc((size_t)N * H);
    unsigned char*  hb   = (unsigned char*)alloc((size_t)N * H);
    __half*         acch = (__half*)alloc((size_t)N * H * 2);
    int*            cnt8 = (int*)alloc((size_t)8 * N * 4);     // zeroed
    unsigned short* rank = (unsigned short*)alloc((size_t)E * 2);
    float*    dinv   = (float*)   alloc((size_t)N * 4);
    float*    dinv2  = (float*)   alloc((size_t)N * 4);
    int*      row_ptr= (int*)     alloc((size_t)(N + 1) * 4);
    int*      bsum   = (int*)     alloc(64 * 4);
    unsigned* ep     = (unsigned*)alloc(EPAD * 4);             // pads zeroed by k_addoff

    hipMemsetAsync(cnt8, 0, (size_t)8 * N * 4, stream);

    // 1) y0 = x @ W1 (fp32 + fp8)
    k_gemm1<<<(N + G1N - 1) / G1N, 256, 0, stream>>>(x, W1, y0, y0f8);

    // 2) per-row edge counts (XCD-local via HW_REG_XCC_ID) + packed ranks
    k_count<<<(E + 255) / 256, 256, 0, stream>>>(row, cnt8, rank);

    // 3) scan (padded degrees) -> row_ptr; fused bsum-prefix + scatter bases
    k_scan_blocks<<<NB, 1024, 0, stream>>>(cnt8, row_ptr, bsum);
    k_addoff<<<NB, 1024, 0, stream>>>(row_ptr, bsum, cnt8, ep);

    // 4) atomic-free scatter, weighted degree + dinv, normalize
    k_scatter<<<(E + 1023) / 1024, 256, 0, stream>>>(row, col, ew, rank, cnt8, ep);
    k_deg_dinv<<<(N + 255) / 256, 256, 0, stream>>>(ep, row_ptr, dinv, dinv2);
    k_norm<<<(N + 31) / 32, 256, 0, stream>>>(ep, row_ptr, dinv);

    // 5) K hops; hop 0 inits acc, hop K-1 fuses the MLP epilogue
    const unsigned* hin = (const unsigned*)y0f8;
    unsigned* bufs[2] = {(unsigned*)ha, (unsigned*)hb};
    const float4* y04 = (const float4*)y0;
    int grid = (N + 15) / 16;
    size_t smemF = (size_t)(H * C + 16 * HSP + C + H) * 4;
    for (int hop = 0; hop < K; ++hop) {
        unsigned* hout = bufs[hop & 1];
        if (hop == 0)
            k_prop<true, true, false><<<grid, 256, 0, stream>>>(hin, hout, acch, dinv2,
                row_ptr, ep, y04, b1, W2, b2, out);
        else if (hop == K - 1)
            k_prop<false, false, true><<<grid, 256, smemF, stream>>>(hin, hout, acch, dinv2,
                row_ptr, ep, y04, b1, W2, b2, out);
        else
            k_prop<true, false, false><<<grid, 256, 0, stream>>>(hin, hout, acch, dinv2,
                row_ptr, ep, y04, b1, W2, b2, out);
        hin = hout;
    }
}

// Round 9
// 279.900 us; speedup vs baseline: 1.0505x; 1.0425x over previous
//
#include <hip/hip_runtime.h>
#include <hip/hip_fp16.h>
#include <math.h>

// Problem constants (fixed by the reference)
constexpr int   N   = 50000;
constexpr int   E   = 600000;
constexpr int   FIN = 128;
constexpr int   H   = 64;
constexpr int   C   = 40;
constexpr int   K   = 10;
constexpr float CK  = (1.0f - 0.1f) / 10.0f;  // (1-alpha)/K
constexpr float AL  = 0.1f;                   // alpha

// Bucket-sort CSR build geometry
constexpr int NBIN = (N + 63) / 64;        // 782 buckets (row >> 6)
constexpr int HB   = (E + 1023) / 1024;    // 586 histogram blocks (1024 edges each)
constexpr int M    = NBIN * HB;            // 458,252 scan elements
constexpr int SB   = (M + 1023) / 1024;    // 448 scan blocks

typedef float v2f __attribute__((ext_vector_type(2)));

// pack 4 fp32 -> 4 fp8 e4m3 (HW RNE, OCP on gfx950)
__device__ __forceinline__ unsigned pack_fp8x4(float f0, float f1, float f2, float f3) {
    unsigned r = __builtin_amdgcn_cvt_pk_fp8_f32(f0, f1, 0u, false);
    r = __builtin_amdgcn_cvt_pk_fp8_f32(f2, f3, r, true);
    return r;
}

// 4-byte edge record: low 16 = col (u16, N<=65535), high 16 = fp16 weight
__device__ __forceinline__ float ep_w(unsigned v) {
    return __half2float(__ushort_as_half((unsigned short)(v >> 16)));
}
__device__ __forceinline__ unsigned ep_pack(int c, float w) {
    return (unsigned)(unsigned short)c |
           ((unsigned)__half_as_ushort(__float2half_rn(w)) << 16);
}

// 4 fp8 (u32) -> 4 fp32, FMA into s[4]
__device__ __forceinline__ void accum4(float* s, unsigned v, float w) {
    v2f p0 = __builtin_amdgcn_cvt_pk_f32_fp8(v, false);
    v2f p1 = __builtin_amdgcn_cvt_pk_f32_fp8(v, true);
    s[0] = fmaf(w, p0.x, s[0]); s[1] = fmaf(w, p0.y, s[1]);
    s[2] = fmaf(w, p1.x, s[2]); s[3] = fmaf(w, p1.y, s[3]);
}

// ---------------------------------------------------------------------------
// y0 = x @ W1   (N x 128) @ (128 x 64)
// ---------------------------------------------------------------------------
constexpr int G1N  = 64;
constexpr int XPAD = 132;
__global__ __launch_bounds__(256, 2) void k_gemm1(const float* __restrict__ x,
                                                  const float* __restrict__ W1,
                                                  float* __restrict__ y0,
                                                  unsigned char* __restrict__ y0f8) {
    __shared__ float ws[FIN * H];
    __shared__ float xs[G1N * XPAD];
    const float4* W14 = (const float4*)W1;
    const float4* x4  = (const float4*)x;
    int t = threadIdx.x;
    int node0 = blockIdx.x * G1N;
    for (int i = t; i < FIN * H / 4; i += 256) ((float4*)ws)[i] = W14[i];
    for (int p = 0; p < 8; ++p) {
        int idx = p * 256 + t;
        int n   = idx >> 5;
        int kk  = idx & 31;
        int node = node0 + n;
        float4 v = (node < N) ? x4[(size_t)node * (FIN / 4) + kk]
                              : make_float4(0.f, 0.f, 0.f, 0.f);
        *(float4*)(xs + n * XPAD + kk * 4) = v;
    }
    __syncthreads();
    int nb = (t >> 4) * 4;
    int cb = (t & 15) * 4;
    float a00=0,a01=0,a02=0,a03=0, a10=0,a11=0,a12=0,a13=0;
    float a20=0,a21=0,a22=0,a23=0, a30=0,a31=0,a32=0,a33=0;
#pragma unroll 8
    for (int k = 0; k < FIN; ++k) {
        float4 wv = *(const float4*)(ws + k * H + cb);
        float x0 = xs[(nb + 0) * XPAD + k];
        float x1 = xs[(nb + 1) * XPAD + k];
        float x2 = xs[(nb + 2) * XPAD + k];
        float x3 = xs[(nb + 3) * XPAD + k];
        a00 = fmaf(x0, wv.x, a00); a01 = fmaf(x0, wv.y, a01);
        a02 = fmaf(x0, wv.z, a02); a03 = fmaf(x0, wv.w, a03);
        a10 = fmaf(x1, wv.x, a10); a11 = fmaf(x1, wv.y, a11);
        a12 = fmaf(x1, wv.z, a12); a13 = fmaf(x1, wv.w, a13);
        a20 = fmaf(x2, wv.x, a20); a21 = fmaf(x2, wv.y, a21);
        a22 = fmaf(x2, wv.z, a22); a23 = fmaf(x2, wv.w, a23);
        a30 = fmaf(x3, wv.x, a30); a31 = fmaf(x3, wv.y, a31);
        a32 = fmaf(x3, wv.z, a32); a33 = fmaf(x3, wv.w, a33);
    }
    float4 rows[4] = {make_float4(a00,a01,a02,a03), make_float4(a10,a11,a12,a13),
                      make_float4(a20,a21,a22,a23), make_float4(a30,a31,a32,a33)};
#pragma unroll
    for (int i = 0; i < 4; ++i) {
        int node = node0 + nb + i;
        if (node >= N) break;
        float4 r = rows[i];
        *(float4*)(y0 + (size_t)node * H + cb) = r;
        *(unsigned*)(y0f8 + (size_t)node * H + cb) = pack_fp8x4(r.x, r.y, r.z, r.w);
    }
}

// ---------------------------------------------------------------------------
// ATOMIC-FREE CSR build (global atomics replaced by LDS histograms):
//   k_hist   : per-block LDS histogram over 782 row-buckets -> bhT[bin][blk]
//   k_scan1/2: exclusive scan of bhT (bin-major) -> global slot bases
//   k_bucket : scatter edges (u64 packed) into bucket-sorted barr via LDS cursors
//   k_cnt    : per-bucket LDS row-count -> cnt[row]  (single copy, fully written)
//   scan_blocks/addoff: padded row_ptr (as before, single-copy)
//   k_emit   : per-bucket LDS row-cursors -> final ep records
// ---------------------------------------------------------------------------
__global__ __launch_bounds__(256) void k_hist(const int* __restrict__ row,
                                              unsigned* __restrict__ bhT) {
    __shared__ unsigned h[NBIN];
    for (int i = threadIdx.x; i < NBIN; i += 256) h[i] = 0;
    __syncthreads();
    int b = blockIdx.x;
    int base = b * 1024 + threadIdx.x;
#pragma unroll
    for (int i = 0; i < 4; ++i) {
        int e = base + i * 256;
        if (e < E) atomicAdd(&h[row[e] >> 6], 1u);
    }
    __syncthreads();
    for (int i = threadIdx.x; i < NBIN; i += 256)
        bhT[(size_t)i * HB + b] = h[i];
}

__global__ __launch_bounds__(1024) void k_scan1(unsigned* __restrict__ S,
                                                unsigned* __restrict__ bsumA) {
    __shared__ unsigned s[1024];
    int gid = blockIdx.x * 1024 + threadIdx.x;
    unsigned v = (gid < M) ? S[gid] : 0;
    s[threadIdx.x] = v;
    __syncthreads();
    for (int off = 1; off < 1024; off <<= 1) {
        unsigned t = (threadIdx.x >= off) ? s[threadIdx.x - off] : 0;
        __syncthreads();
        s[threadIdx.x] += t;
        __syncthreads();
    }
    if (gid < M) S[gid] = s[threadIdx.x] - v;   // exclusive (block-local)
    if (threadIdx.x == 1023) bsumA[blockIdx.x] = s[1023];
}

__global__ __launch_bounds__(512) void k_scan2(unsigned* __restrict__ bsumA) {
    __shared__ unsigned s[512];
    int t = threadIdx.x;
    unsigned v = (t < SB) ? bsumA[t] : 0;
    s[t] = v;
    __syncthreads();
    for (int off = 1; off < 512; off <<= 1) {
        unsigned x = (t >= off) ? s[t - off] : 0;
        __syncthreads();
        s[t] += x;
        __syncthreads();
    }
    if (t < SB) bsumA[t] = s[t] - v;            // exclusive block offsets
}

__global__ __launch_bounds__(256) void k_bucket(const int* __restrict__ row,
                                                const int* __restrict__ col,
                                                const float* __restrict__ w,
                                                const unsigned* __restrict__ S,
                                                const unsigned* __restrict__ bofs,
                                                unsigned long long* __restrict__ barr) {
    __shared__ unsigned cur[NBIN];
    int b = blockIdx.x;
    for (int i = threadIdx.x; i < NBIN; i += 256) {
        unsigned idx = (unsigned)i * HB + (unsigned)b;
        cur[i] = S[idx] + bofs[idx >> 10];
    }
    __syncthreads();
    int base = b * 1024 + threadIdx.x;
#pragma unroll
    for (int i = 0; i < 4; ++i) {
        int e = base + i * 256;
        if (e < E) {
            int r = row[e];
            unsigned p = atomicAdd(&cur[r >> 6], 1u);     // LDS atomic (fast)
            unsigned short wh = __half_as_ushort(__float2half_rn(w[e]));
            barr[p] = ((unsigned long long)wh << 32) |
                      ((unsigned long long)(unsigned)r << 16) |
                      (unsigned long long)(unsigned)col[e];
        }
    }
}

__device__ __forceinline__ unsigned bucket_lo(const unsigned* S, const unsigned* bofs,
                                              int bin) {
    unsigned idx = (unsigned)bin * HB;
    return S[idx] + bofs[idx >> 10];
}

__global__ __launch_bounds__(256) void k_cnt(const unsigned long long* __restrict__ barr,
                                             const unsigned* __restrict__ S,
                                             const unsigned* __restrict__ bofs,
                                             int* __restrict__ cnt) {
    __shared__ unsigned rc[64];
    if (threadIdx.x < 64) rc[threadIdx.x] = 0;
    __syncthreads();
    int bin = blockIdx.x;
    unsigned i0 = bucket_lo(S, bofs, bin);
    unsigned i1 = (bin + 1 < NBIN) ? bucket_lo(S, bofs, bin + 1) : (unsigned)E;
    for (unsigned i = i0 + threadIdx.x; i < i1; i += 256) {
        unsigned r = (unsigned)(barr[i] >> 16) & 0xFFFFu;
        atomicAdd(&rc[r & 63], 1u);
    }
    __syncthreads();
    int r0 = bin * 64;
    if (threadIdx.x < 64 && r0 + (int)threadIdx.x < N)
        cnt[r0 + threadIdx.x] = (int)rc[threadIdx.x];
}

// Two-level exclusive scan of PADDED (align-4) degrees -> row_ptr[]
__global__ __launch_bounds__(1024) void k_scan_blocks(const int* __restrict__ cnt,
                                                      int* __restrict__ row_ptr,
                                                      int* __restrict__ bsum) {
    __shared__ int s[1024];
    int gid = blockIdx.x * 1024 + threadIdx.x;
    int v = 0;
    if (gid < N) v = (cnt[gid] + 3) & ~3;   // pad row to multiple of 4 records
    s[threadIdx.x] = v;
    __syncthreads();
    for (int off = 1; off < 1024; off <<= 1) {
        int t = (threadIdx.x >= off) ? s[threadIdx.x - off] : 0;
        __syncthreads();
        s[threadIdx.x] += t;
        __syncthreads();
    }
    if (gid < N) row_ptr[gid] = s[threadIdx.x] - v;  // exclusive
    if (threadIdx.x == 1023) bsum[blockIdx.x] = s[1023];
}

constexpr int NB = (N + 1023) / 1024;  // 49
__global__ __launch_bounds__(1024) void k_addoff(int* __restrict__ row_ptr,
                                                 const int* __restrict__ bsum,
                                                 const int* __restrict__ cnt,
                                                 unsigned* __restrict__ ep) {
    __shared__ int sboff;
    __shared__ int stot;
    if (threadIdx.x < 64) {
        int lane = threadIdx.x;
        int orig = (lane < NB) ? bsum[lane] : 0;
        int v = orig;
        for (int off = 1; off < 64; off <<= 1) {
            int t = __shfl_up(v, off, 64);
            if (lane >= off) v += t;
        }
        if (lane == (int)blockIdx.x) sboff = v - orig;   // exclusive prefix
        if (lane == NB - 1)          stot  = v;          // total padded records
    }
    __syncthreads();
    int gid = blockIdx.x * 1024 + threadIdx.x;
    if (gid < N) {
        int rp = row_ptr[gid] + sboff;
        row_ptr[gid] = rp;
        int real = cnt[gid];
        int pd = (real + 3) & ~3;
        for (int j = real; j < pd; ++j) ep[rp + j] = 0u;   // zero pad slots
    }
    if (gid == 0) {
        row_ptr[N] = stot;
        *(uint4*)(ep + stot) = make_uint4(0u, 0u, 0u, 0u); // 16 B tail
    }
}

__global__ __launch_bounds__(256) void k_emit(const unsigned long long* __restrict__ barr,
                                              const unsigned* __restrict__ S,
                                              const unsigned* __restrict__ bofs,
                                              const int* __restrict__ row_ptr,
                                              unsigned* __restrict__ ep) {
    __shared__ unsigned cur[64];
    int bin = blockIdx.x;
    int r0 = bin * 64;
    if (threadIdx.x < 64) {
        int r = r0 + (int)threadIdx.x;
        cur[threadIdx.x] = (r < N) ? (unsigned)row_ptr[r] : 0u;
    }
    __syncthreads();
    unsigned i0 = bucket_lo(S, bofs, bin);
    unsigned i1 = (bin + 1 < NBIN) ? bucket_lo(S, bofs, bin + 1) : (unsigned)E;
    for (unsigned i = i0 + threadIdx.x; i < i1; i += 256) {
        unsigned long long v = barr[i];
        unsigned r = (unsigned)(v >> 16) & 0xFFFFu;
        unsigned p = atomicAdd(&cur[r & 63], 1u);          // LDS cursor
        ep[p] = (unsigned)(v & 0xFFFFu) | (((unsigned)(v >> 32) & 0xFFFFu) << 16);
    }
}

// ---------------------------------------------------------------------------
// Weighted degree (vectorized: 8 lanes/node, uint4 loads over padded rows;
// pads contribute 0) + dinv/dinv2
// ---------------------------------------------------------------------------
__global__ __launch_bounds__(256) void k_deg_dinv(const unsigned* __restrict__ ep,
                                                  const int* __restrict__ row_ptr,
                                                  float* __restrict__ dinv,
                                                  float* __restrict__ dinv2) {
    int node = blockIdx.x * 32 + (threadIdx.x >> 3);
    if (node >= N) return;
    int l = threadIdx.x & 7;
    int e0 = row_ptr[node], e1 = row_ptr[node + 1];
    float d = 0.f;
    for (int j4 = (e0 >> 2) + l; j4 * 4 < e1; j4 += 8) {
        uint4 v = ((const uint4*)ep)[j4];
        d += ep_w(v.x) + ep_w(v.y) + ep_w(v.z) + ep_w(v.w);
    }
    d += __shfl_xor(d, 1, 64);
    d += __shfl_xor(d, 2, 64);
    d += __shfl_xor(d, 4, 64);
    if (l == 0) {
        d += 1.0f;   // self-loop weight
        float di = rsqrtf(d);
        dinv[node]  = di;
        dinv2[node] = di * di;
    }
}

// ---------------------------------------------------------------------------
// Normalize edge weights in place (vectorized uint4; pads stay 0)
// ---------------------------------------------------------------------------
__global__ __launch_bounds__(256) void k_norm(unsigned* __restrict__ ep,
                                              const int* __restrict__ row_ptr,
                                              const float* __restrict__ dinv) {
    int node = blockIdx.x * 32 + (threadIdx.x >> 3);
    if (node >= N) return;
    int l = threadIdx.x & 7;
    float dr = dinv[node];
    int e0 = row_ptr[node], e1 = row_ptr[node + 1];
    for (int j4 = (e0 >> 2) + l; j4 * 4 < e1; j4 += 8) {
        uint4 v = ((uint4*)ep)[j4];
        v.x = ep_pack(v.x & 0xFFFFu, ep_w(v.x) * dr * dinv[v.x & 0xFFFFu]);
        v.y = ep_pack(v.y & 0xFFFFu, ep_w(v.y) * dr * dinv[v.y & 0xFFFFu]);
        v.z = ep_pack(v.z & 0xFFFFu, ep_w(v.z) * dr * dinv[v.z & 0xFFFFu]);
        v.w = ep_pack(v.w & 0xFFFFu, ep_w(v.w) * dr * dinv[v.w & 0xFFFFu]);
        ((uint4*)ep)[j4] = v;
    }
}

// ---------------------------------------------------------------------------
// One propagation hop (r6-best, unchanged), fp8 h storage, padded records.
// 16 lanes/node (4 nodes/wave), two uint4 records double-prefetched,
// 8 gathers in flight. 16 nodes/block. acc fp16 in global.
// FINAL fuses the MLP epilogue.
// ---------------------------------------------------------------------------
constexpr int HSP = 68;
template <bool WRITE_H, bool ACC_INIT, bool FINAL>
__global__ __launch_bounds__(256) void k_prop(const unsigned* __restrict__ hin,  // N x 16 u32
                                              unsigned* __restrict__ hout,
                                              __half* __restrict__ acch,         // N x H fp16
                                              const float* __restrict__ dinv2,
                                              const int* __restrict__ row_ptr,
                                              const unsigned* __restrict__ ep,
                                              const float4* __restrict__ y04,
                                              const float* __restrict__ b1,
                                              const float* __restrict__ W2,
                                              const float* __restrict__ b2,
                                              float* __restrict__ out) {
    extern __shared__ float smem[];          // FINAL only: w2s | hs | b2s | b1s
    float* w2s = smem;
    float* hs  = smem + H * C;
    float* b2s = hs + 16 * HSP;
    float* b1s = b2s + C;
    int t = threadIdx.x;
    if (FINAL) {
        for (int i = t; i < H * C; i += 256) w2s[i] = W2[i];
        if (t < C) b2s[t] = b2[t];
        if (t < H) b1s[t] = b1[t];
        __syncthreads();
    }
    int lane = t & 63;
    int nib  = (t >> 6) * 4 + (lane >> 4);   // node-in-block 0..15
    int l    = lane & 15;                    // feature quad (4 fp8)
    int node = blockIdx.x * 16 + nib;
    bool nv  = node < N;
    int nodec = nv ? node : N - 1;
    int start = row_ptr[nodec];
    int pdeg  = nv ? (row_ptr[nodec + 1] - start) : 0;   // padded degree (mult of 4)
    int md = pdeg;
#pragma unroll
    for (int off = 16; off <= 32; off <<= 1) md = max(md, __shfl_xor(md, off, 64));

    size_t base = (size_t)nodec * 16 + l;
    unsigned vself = hin[base];
    float d2       = dinv2[nodec];
    uint2* ap = (uint2*)(acch + (size_t)nodec * H + l * 4);
    uint2 old;
    if (nv && (FINAL || !ACC_INIT)) old = *ap;

    float s[4];
#pragma unroll
    for (int i = 0; i < 4; ++i) s[i] = 0.f;

    const unsigned* rp = ep + start;
    uint4 ea = *(const uint4*)rp;                               // slots 0..3
    uint4 eb = *(const uint4*)(rp + ((4 < pdeg) ? 4 : 0));      // slots 4..7
    for (int batch = 0; batch < md; batch += 8) {
        uint4 ca = ea, cb = eb;
        int n0 = batch + 8, n1 = batch + 12;
        ea = *(const uint4*)(rp + ((n0 < pdeg) ? n0 : 0));      // prefetch next step
        eb = *(const uint4*)(rp + ((n1 < pdeg) ? n1 : 0));
        unsigned v0 = hin[(size_t)(ca.x & 0xFFFFu) * 16 + l];
        unsigned v1 = hin[(size_t)(ca.y & 0xFFFFu) * 16 + l];
        unsigned v2 = hin[(size_t)(ca.z & 0xFFFFu) * 16 + l];
        unsigned v3 = hin[(size_t)(ca.w & 0xFFFFu) * 16 + l];
        unsigned v4 = hin[(size_t)(cb.x & 0xFFFFu) * 16 + l];
        unsigned v5 = hin[(size_t)(cb.y & 0xFFFFu) * 16 + l];
        unsigned v6 = hin[(size_t)(cb.z & 0xFFFFu) * 16 + l];
        unsigned v7 = hin[(size_t)(cb.w & 0xFFFFu) * 16 + l];
        accum4(s, v0, (batch     < pdeg) ? ep_w(ca.x) : 0.0f);
        accum4(s, v1, (batch + 1 < pdeg) ? ep_w(ca.y) : 0.0f);
        accum4(s, v2, (batch + 2 < pdeg) ? ep_w(ca.z) : 0.0f);
        accum4(s, v3, (batch + 3 < pdeg) ? ep_w(ca.w) : 0.0f);
        accum4(s, v4, (batch + 4 < pdeg) ? ep_w(cb.x) : 0.0f);
        accum4(s, v5, (batch + 5 < pdeg) ? ep_w(cb.y) : 0.0f);
        accum4(s, v6, (batch + 6 < pdeg) ? ep_w(cb.z) : 0.0f);
        accum4(s, v7, (batch + 7 < pdeg) ? ep_w(cb.w) : 0.0f);
    }
    if (nv) {
        accum4(s, vself, d2);                    // self-loop term (order preserved)
        if (WRITE_H) {
            hout[base] = pack_fp8x4(s[0], s[1], s[2], s[3]);
        }
        if (FINAL) {
            const unsigned* u = (const unsigned*)&old;
#pragma unroll
            for (int d = 0; d < 2; ++d) {
                float2 f = __half22float2(*(__half2*)&u[d]);
                s[2*d+0] += f.x; s[2*d+1] += f.y;
            }
            float4 ya = y04[(size_t)nodec * (H / 4) + l];
            const float* bp = b1s + l * 4;
            float* hp = hs + nib * HSP + l * 4;
            hp[0] = fmaxf(fmaf(CK, s[0], fmaf(AL, ya.x, bp[0])), 0.f);
            hp[1] = fmaxf(fmaf(CK, s[1], fmaf(AL, ya.y, bp[1])), 0.f);
            hp[2] = fmaxf(fmaf(CK, s[2], fmaf(AL, ya.z, bp[2])), 0.f);
            hp[3] = fmaxf(fmaf(CK, s[3], fmaf(AL, ya.w, bp[3])), 0.f);
        } else {
            if (!ACC_INIT) {
                const unsigned* u = (const unsigned*)&old;
#pragma unroll
                for (int d = 0; d < 2; ++d) {
                    float2 f = __half22float2(*(__half2*)&u[d]);
                    s[2*d+0] += f.x; s[2*d+1] += f.y;
                }
            }
            uint2 nvp;
            unsigned* u = (unsigned*)&nvp;
#pragma unroll
            for (int d = 0; d < 2; ++d) {
                __half2 h = __floats2half2_rn(s[2*d+0], s[2*d+1]);
                u[d] = *(unsigned*)&h;
            }
            *ap = nvp;
        }
    }
    if (FINAL) {
        __syncthreads();
        int node0 = blockIdx.x * 16;
        for (int o = t; o < 16 * C; o += 256) {
            int nl = o / C, c = o % C;
            int n2 = node0 + nl;
            if (n2 >= N) continue;
            float v = b2s[c];
            const float* hr = &hs[nl * HSP];
#pragma unroll
            for (int k = 0; k < H; ++k) v = fmaf(hr[k], w2s[k * C + c], v);
            out[n2 * C + c] = v;
        }
    }
}

// ---------------------------------------------------------------------------
extern "C" void kernel_launch(void* const* d_in, const int* in_sizes, int n_in,
                              void* d_out, int out_size, void* d_ws, size_t ws_size,
                              hipStream_t stream) {
    const float* x  = (const float*)d_in[0];
    const int*   ei = (const int*)d_in[1];
    const float* ew = (const float*)d_in[2];
    const float* W1 = (const float*)d_in[3];
    const float* b1 = (const float*)d_in[4];
    const float* W2 = (const float*)d_in[5];
    const float* b2 = (const float*)d_in[6];
    float* out = (float*)d_out;

    const int* row = ei;
    const int* col = ei + E;

    char* ws = (char*)d_ws;
    size_t off = 0;
    auto alloc = [&](size_t bytes) -> char* {
        char* p = ws + off;
        off = (off + bytes + 1023) & ~(size_t)1023;
        return p;
    };
    constexpr size_t EPAD = (size_t)E + 3 * (size_t)N + 1024;  // padded CSR capacity
    float*              y0    = (float*)alloc((size_t)N * H * 4);
    unsigned char*      y0f8  = (unsigned char*)alloc((size_t)N * H);
    unsigned char*      ha    = (unsigned char*)alloc((size_t)N * H);
    unsigned char*      hb    = (unsigned char*)alloc((size_t)N * H);
    __half*             acch  = (__half*)alloc((size_t)N * H * 2);
    int*                cnt   = (int*)alloc((size_t)N * 4);       // fully written by k_cnt
    unsigned*           bhT   = (unsigned*)alloc((size_t)M * 4);  // fully written by k_hist
    unsigned*           bsumA = (unsigned*)alloc(512 * 4);
    unsigned long long* barr  = (unsigned long long*)alloc((size_t)E * 8);
    float*    dinv    = (float*)alloc((size_t)N * 4);
    float*    dinv2   = (float*)alloc((size_t)N * 4);
    int*      row_ptr = (int*)alloc((size_t)(N + 1) * 4);
    int*      bsum    = (int*)alloc(64 * 4);
    unsigned* ep      = (unsigned*)alloc(EPAD * 4);               // pads zeroed by k_addoff

    // 1) y0 = x @ W1 (fp32 + fp8)
    k_gemm1<<<(N + G1N - 1) / G1N, 256, 0, stream>>>(x, W1, y0, y0f8);

    // 2) atomic-free CSR build (LDS bucket sort by row>>6)
    k_hist  <<<HB, 256, 0, stream>>>(row, bhT);
    k_scan1 <<<SB, 1024, 0, stream>>>(bhT, bsumA);
    k_scan2 <<<1, 512, 0, stream>>>(bsumA);
    k_bucket<<<HB, 256, 0, stream>>>(row, col, ew, bhT, bsumA, barr);
    k_cnt   <<<NBIN, 256, 0, stream>>>(barr, bhT, bsumA, cnt);

    // 3) scan (padded degrees) -> row_ptr; fused bsum-prefix + pad zeroing
    k_scan_blocks<<<NB, 1024, 0, stream>>>(cnt, row_ptr, bsum);
    k_addoff<<<NB, 1024, 0, stream>>>(row_ptr, bsum, cnt, ep);

    // 4) emit CSR records, weighted degree + dinv, normalize
    k_emit<<<NBIN, 256, 0, stream>>>(barr, bhT, bsumA, row_ptr, ep);
    k_deg_dinv<<<(N + 31) / 32, 256, 0, stream>>>(ep, row_ptr, dinv, dinv2);
    k_norm<<<(N + 31) / 32, 256, 0, stream>>>(ep, row_ptr, dinv);

    // 5) K hops; hop 0 inits acc, hop K-1 fuses the MLP epilogue
    const unsigned* hin = (const unsigned*)y0f8;
    unsigned* bufs[2] = {(unsigned*)ha, (unsigned*)hb};
    const float4* y04 = (const float4*)y0;
    int grid = (N + 15) / 16;
    size_t smemF = (size_t)(H * C + 16 * HSP + C + H) * 4;
    for (int hop = 0; hop < K; ++hop) {
        unsigned* hout = bufs[hop & 1];
        if (hop == 0)
            k_prop<true, true, false><<<grid, 256, 0, stream>>>(hin, hout, acch, dinv2,
                row_ptr, ep, y04, b1, W2, b2, out);
        else if (hop == K - 1)
            k_prop<false, false, true><<<grid, 256, smemF, stream>>>(hin, hout, acch, dinv2,
                row_ptr, ep, y04, b1, W2, b2, out);
        else
            k_prop<true, false, false><<<grid, 256, 0, stream>>>(hin, hout, acch, dinv2,
                row_ptr, ep, y04, b1, W2, b2, out);
        hin = hout;
    }
}

// Round 10
// 277.907 us; speedup vs baseline: 1.0580x; 1.0072x over previous
//
#include <hip/hip_runtime.h>
#include <hip/hip_fp16.h>
#include <math.h>

// Problem constants (fixed by the reference)
constexpr int   N   = 50000;
constexpr int   E   = 600000;
constexpr int   FIN = 128;
constexpr int   H   = 64;
constexpr int   C   = 40;
constexpr int   K   = 10;
constexpr float CK  = (1.0f - 0.1f) / 10.0f;  // (1-alpha)/K
constexpr float AL  = 0.1f;                   // alpha

// Bucket-sort CSR build geometry
constexpr int NBIN = (N + 63) / 64;        // 782 buckets (row >> 6)
constexpr int HB   = (E + 1023) / 1024;    // 586 histogram blocks (1024 edges each)
constexpr int M    = NBIN * HB;            // 458,252 scan elements
constexpr int SB   = (M + 1023) / 1024;    // 448 scan blocks

typedef float v2f __attribute__((ext_vector_type(2)));

// pack 4 fp32 -> 4 fp8 e4m3 (HW RNE, OCP on gfx950)
__device__ __forceinline__ unsigned pack_fp8x4(float f0, float f1, float f2, float f3) {
    unsigned r = __builtin_amdgcn_cvt_pk_fp8_f32(f0, f1, 0u, false);
    r = __builtin_amdgcn_cvt_pk_fp8_f32(f2, f3, r, true);
    return r;
}

// 4-byte edge record: low 16 = col (u16, N<=65535), high 16 = fp16 weight
__device__ __forceinline__ float ep_w(unsigned v) {
    return __half2float(__ushort_as_half((unsigned short)(v >> 16)));
}
__device__ __forceinline__ unsigned ep_pack(int c, float w) {
    return (unsigned)(unsigned short)c |
           ((unsigned)__half_as_ushort(__float2half_rn(w)) << 16);
}

// 4 fp8 (u32) -> 4 fp32, FMA into s[4]
__device__ __forceinline__ void accum4(float* s, unsigned v, float w) {
    v2f p0 = __builtin_amdgcn_cvt_pk_f32_fp8(v, false);
    v2f p1 = __builtin_amdgcn_cvt_pk_f32_fp8(v, true);
    s[0] = fmaf(w, p0.x, s[0]); s[1] = fmaf(w, p0.y, s[1]);
    s[2] = fmaf(w, p1.x, s[2]); s[3] = fmaf(w, p1.y, s[3]);
}

// ---------------------------------------------------------------------------
// y0 = x @ W1   (N x 128) @ (128 x 64)
// ---------------------------------------------------------------------------
constexpr int G1N  = 64;
constexpr int XPAD = 132;
__global__ __launch_bounds__(256, 2) void k_gemm1(const float* __restrict__ x,
                                                  const float* __restrict__ W1,
                                                  float* __restrict__ y0,
                                                  unsigned char* __restrict__ y0f8) {
    __shared__ float ws[FIN * H];
    __shared__ float xs[G1N * XPAD];
    const float4* W14 = (const float4*)W1;
    const float4* x4  = (const float4*)x;
    int t = threadIdx.x;
    int node0 = blockIdx.x * G1N;
    for (int i = t; i < FIN * H / 4; i += 256) ((float4*)ws)[i] = W14[i];
    for (int p = 0; p < 8; ++p) {
        int idx = p * 256 + t;
        int n   = idx >> 5;
        int kk  = idx & 31;
        int node = node0 + n;
        float4 v = (node < N) ? x4[(size_t)node * (FIN / 4) + kk]
                              : make_float4(0.f, 0.f, 0.f, 0.f);
        *(float4*)(xs + n * XPAD + kk * 4) = v;
    }
    __syncthreads();
    int nb = (t >> 4) * 4;
    int cb = (t & 15) * 4;
    float a00=0,a01=0,a02=0,a03=0, a10=0,a11=0,a12=0,a13=0;
    float a20=0,a21=0,a22=0,a23=0, a30=0,a31=0,a32=0,a33=0;
#pragma unroll 8
    for (int k = 0; k < FIN; ++k) {
        float4 wv = *(const float4*)(ws + k * H + cb);
        float x0 = xs[(nb + 0) * XPAD + k];
        float x1 = xs[(nb + 1) * XPAD + k];
        float x2 = xs[(nb + 2) * XPAD + k];
        float x3 = xs[(nb + 3) * XPAD + k];
        a00 = fmaf(x0, wv.x, a00); a01 = fmaf(x0, wv.y, a01);
        a02 = fmaf(x0, wv.z, a02); a03 = fmaf(x0, wv.w, a03);
        a10 = fmaf(x1, wv.x, a10); a11 = fmaf(x1, wv.y, a11);
        a12 = fmaf(x1, wv.z, a12); a13 = fmaf(x1, wv.w, a13);
        a20 = fmaf(x2, wv.x, a20); a21 = fmaf(x2, wv.y, a21);
        a22 = fmaf(x2, wv.z, a22); a23 = fmaf(x2, wv.w, a23);
        a30 = fmaf(x3, wv.x, a30); a31 = fmaf(x3, wv.y, a31);
        a32 = fmaf(x3, wv.z, a32); a33 = fmaf(x3, wv.w, a33);
    }
    float4 rows[4] = {make_float4(a00,a01,a02,a03), make_float4(a10,a11,a12,a13),
                      make_float4(a20,a21,a22,a23), make_float4(a30,a31,a32,a33)};
#pragma unroll
    for (int i = 0; i < 4; ++i) {
        int node = node0 + nb + i;
        if (node >= N) break;
        float4 r = rows[i];
        *(float4*)(y0 + (size_t)node * H + cb) = r;
        *(unsigned*)(y0f8 + (size_t)node * H + cb) = pack_fp8x4(r.x, r.y, r.z, r.w);
    }
}

// ---------------------------------------------------------------------------
// ATOMIC-FREE CSR build (LDS bucket sort by row>>6) — r9 structure.
// ---------------------------------------------------------------------------
__global__ __launch_bounds__(256) void k_hist(const int* __restrict__ row,
                                              unsigned* __restrict__ bhT) {
    __shared__ unsigned h[NBIN];
    for (int i = threadIdx.x; i < NBIN; i += 256) h[i] = 0;
    __syncthreads();
    int b = blockIdx.x;
    int base = b * 1024 + threadIdx.x;
#pragma unroll
    for (int i = 0; i < 4; ++i) {
        int e = base + i * 256;
        if (e < E) atomicAdd(&h[row[e] >> 6], 1u);
    }
    __syncthreads();
    for (int i = threadIdx.x; i < NBIN; i += 256)
        bhT[(size_t)i * HB + b] = h[i];
}

__global__ __launch_bounds__(1024) void k_scan1(unsigned* __restrict__ S,
                                                unsigned* __restrict__ bsumA) {
    __shared__ unsigned s[1024];
    int gid = blockIdx.x * 1024 + threadIdx.x;
    unsigned v = (gid < M) ? S[gid] : 0;
    s[threadIdx.x] = v;
    __syncthreads();
    for (int off = 1; off < 1024; off <<= 1) {
        unsigned t = (threadIdx.x >= off) ? s[threadIdx.x - off] : 0;
        __syncthreads();
        s[threadIdx.x] += t;
        __syncthreads();
    }
    if (gid < M) S[gid] = s[threadIdx.x] - v;   // exclusive (block-local)
    if (threadIdx.x == 1023) bsumA[blockIdx.x] = s[1023];
}

__global__ __launch_bounds__(512) void k_scan2(unsigned* __restrict__ bsumA) {
    __shared__ unsigned s[512];
    int t = threadIdx.x;
    unsigned v = (t < SB) ? bsumA[t] : 0;
    s[t] = v;
    __syncthreads();
    for (int off = 1; off < 512; off <<= 1) {
        unsigned x = (t >= off) ? s[t - off] : 0;
        __syncthreads();
        s[t] += x;
        __syncthreads();
    }
    if (t < SB) bsumA[t] = s[t] - v;            // exclusive block offsets
}

__global__ __launch_bounds__(256) void k_bucket(const int* __restrict__ row,
                                                const int* __restrict__ col,
                                                const float* __restrict__ w,
                                                const unsigned* __restrict__ S,
                                                const unsigned* __restrict__ bofs,
                                                unsigned long long* __restrict__ barr) {
    __shared__ unsigned cur[NBIN];
    int b = blockIdx.x;
    for (int i = threadIdx.x; i < NBIN; i += 256) {
        unsigned idx = (unsigned)i * HB + (unsigned)b;
        cur[i] = S[idx] + bofs[idx >> 10];
    }
    __syncthreads();
    int base = b * 1024 + threadIdx.x;
#pragma unroll
    for (int i = 0; i < 4; ++i) {
        int e = base + i * 256;
        if (e < E) {
            int r = row[e];
            unsigned p = atomicAdd(&cur[r >> 6], 1u);     // LDS atomic (fast)
            unsigned short wh = __half_as_ushort(__float2half_rn(w[e]));
            barr[p] = ((unsigned long long)wh << 32) |
                      ((unsigned long long)(unsigned)r << 16) |
                      (unsigned long long)(unsigned)col[e];
        }
    }
}

__device__ __forceinline__ unsigned bucket_lo(const unsigned* S, const unsigned* bofs,
                                              int bin) {
    unsigned idx = (unsigned)bin * HB;
    return S[idx] + bofs[idx >> 10];
}

__global__ __launch_bounds__(256) void k_cnt(const unsigned long long* __restrict__ barr,
                                             const unsigned* __restrict__ S,
                                             const unsigned* __restrict__ bofs,
                                             int* __restrict__ cnt) {
    __shared__ unsigned rc[64];
    if (threadIdx.x < 64) rc[threadIdx.x] = 0;
    __syncthreads();
    int bin = blockIdx.x;
    unsigned i0 = bucket_lo(S, bofs, bin);
    unsigned i1 = (bin + 1 < NBIN) ? bucket_lo(S, bofs, bin + 1) : (unsigned)E;
    for (unsigned i = i0 + threadIdx.x; i < i1; i += 256) {
        unsigned r = (unsigned)(barr[i] >> 16) & 0xFFFFu;
        atomicAdd(&rc[r & 63], 1u);
    }
    __syncthreads();
    int r0 = bin * 64;
    if (threadIdx.x < 64 && r0 + (int)threadIdx.x < N)
        cnt[r0 + threadIdx.x] = (int)rc[threadIdx.x];
}

// Two-level exclusive scan of PADDED (align-4) degrees -> row_ptr[]
__global__ __launch_bounds__(1024) void k_scan_blocks(const int* __restrict__ cnt,
                                                      int* __restrict__ row_ptr,
                                                      int* __restrict__ bsum) {
    __shared__ int s[1024];
    int gid = blockIdx.x * 1024 + threadIdx.x;
    int v = 0;
    if (gid < N) v = (cnt[gid] + 3) & ~3;   // pad row to multiple of 4 records
    s[threadIdx.x] = v;
    __syncthreads();
    for (int off = 1; off < 1024; off <<= 1) {
        int t = (threadIdx.x >= off) ? s[threadIdx.x - off] : 0;
        __syncthreads();
        s[threadIdx.x] += t;
        __syncthreads();
    }
    if (gid < N) row_ptr[gid] = s[threadIdx.x] - v;  // exclusive
    if (threadIdx.x == 1023) bsum[blockIdx.x] = s[1023];
}

constexpr int NB = (N + 1023) / 1024;  // 49
__global__ __launch_bounds__(1024) void k_addoff(int* __restrict__ row_ptr,
                                                 const int* __restrict__ bsum,
                                                 const int* __restrict__ cnt,
                                                 unsigned* __restrict__ ep) {
    __shared__ int sboff;
    __shared__ int stot;
    if (threadIdx.x < 64) {
        int lane = threadIdx.x;
        int orig = (lane < NB) ? bsum[lane] : 0;
        int v = orig;
        for (int off = 1; off < 64; off <<= 1) {
            int t = __shfl_up(v, off, 64);
            if (lane >= off) v += t;
        }
        if (lane == (int)blockIdx.x) sboff = v - orig;   // exclusive prefix
        if (lane == NB - 1)          stot  = v;          // total padded records
    }
    __syncthreads();
    int gid = blockIdx.x * 1024 + threadIdx.x;
    if (gid < N) {
        int rp = row_ptr[gid] + sboff;
        row_ptr[gid] = rp;
        int real = cnt[gid];
        int pd = (real + 3) & ~3;
        for (int j = real; j < pd; ++j) ep[rp + j] = 0u;   // zero pad slots
    }
    if (gid == 0) {
        row_ptr[N] = stot;
        *(uint4*)(ep + stot) = make_uint4(0u, 0u, 0u, 0u); // 16 B tail
    }
}

// Emit CSR records AND per-row weighted degree -> dinv/dinv2 (fused: a bucket
// holds the COMPLETE edge set of its 64 rows).
__global__ __launch_bounds__(256) void k_emit(const unsigned long long* __restrict__ barr,
                                              const unsigned* __restrict__ S,
                                              const unsigned* __restrict__ bofs,
                                              const int* __restrict__ row_ptr,
                                              unsigned* __restrict__ ep,
                                              float* __restrict__ dinv,
                                              float* __restrict__ dinv2) {
    __shared__ unsigned cur[64];
    __shared__ float wsum[64];
    int bin = blockIdx.x;
    int r0 = bin * 64;
    if (threadIdx.x < 64) {
        int r = r0 + (int)threadIdx.x;
        cur[threadIdx.x] = (r < N) ? (unsigned)row_ptr[r] : 0u;
        wsum[threadIdx.x] = 0.f;
    }
    __syncthreads();
    unsigned i0 = bucket_lo(S, bofs, bin);
    unsigned i1 = (bin + 1 < NBIN) ? bucket_lo(S, bofs, bin + 1) : (unsigned)E;
    for (unsigned i = i0 + threadIdx.x; i < i1; i += 256) {
        unsigned long long v = barr[i];
        unsigned r = (unsigned)(v >> 16) & 0xFFFFu;
        unsigned wh = (unsigned)(v >> 32) & 0xFFFFu;
        unsigned p = atomicAdd(&cur[r & 63], 1u);          // LDS cursor
        ep[p] = (unsigned)(v & 0xFFFFu) | (wh << 16);
        atomicAdd(&wsum[r & 63], __half2float(__ushort_as_half((unsigned short)wh)));
    }
    __syncthreads();
    if (threadIdx.x < 64) {
        int r = r0 + (int)threadIdx.x;
        if (r < N) {
            float d = 1.0f + wsum[threadIdx.x];   // self-loop weight
            float di = rsqrtf(d);
            dinv[r]  = di;
            dinv2[r] = di * di;
        }
    }
}

// ---------------------------------------------------------------------------
// Normalize edge weights in place (vectorized uint4; pads stay 0)
// ---------------------------------------------------------------------------
__global__ __launch_bounds__(256) void k_norm(unsigned* __restrict__ ep,
                                              const int* __restrict__ row_ptr,
                                              const float* __restrict__ dinv) {
    int node = blockIdx.x * 32 + (threadIdx.x >> 3);
    if (node >= N) return;
    int l = threadIdx.x & 7;
    float dr = dinv[node];
    int e0 = row_ptr[node], e1 = row_ptr[node + 1];
    for (int j4 = (e0 >> 2) + l; j4 * 4 < e1; j4 += 8) {
        uint4 v = ((uint4*)ep)[j4];
        v.x = ep_pack(v.x & 0xFFFFu, ep_w(v.x) * dr * dinv[v.x & 0xFFFFu]);
        v.y = ep_pack(v.y & 0xFFFFu, ep_w(v.y) * dr * dinv[v.y & 0xFFFFu]);
        v.z = ep_pack(v.z & 0xFFFFu, ep_w(v.z) * dr * dinv[v.z & 0xFFFFu]);
        v.w = ep_pack(v.w & 0xFFFFu, ep_w(v.w) * dr * dinv[v.w & 0xFFFFu]);
        ((uint4*)ep)[j4] = v;
    }
}

// ---------------------------------------------------------------------------
// One propagation hop. NO acch RMW: the hop result s is NT-streamed (bypasses
// L2, holds no MSHR) into an independent fp16 slice haccl; k_mlp sums slices.
// This cuts hop line-fills ~24%/CU and shrinks the hop's per-XCD L2 working
// set to hin 3.2 + ep 0.3 + hout 0.4 = 3.9 MB <= 4 MB -> hin L2-resident.
// 16 lanes/node (4 nodes/wave), two uint4 records double-prefetched,
// 8 gathers in flight. 16 nodes/block.
// ---------------------------------------------------------------------------
template <bool WRITE_H>
__global__ __launch_bounds__(256) void k_prop(const unsigned* __restrict__ hin,  // N x 16 u32
                                              unsigned* __restrict__ hout,
                                              __half* __restrict__ haccl,        // N x H fp16 slice
                                              const float* __restrict__ dinv2,
                                              const int* __restrict__ row_ptr,
                                              const unsigned* __restrict__ ep) {
    int t = threadIdx.x;
    int lane = t & 63;
    int nib  = (t >> 6) * 4 + (lane >> 4);   // node-in-block 0..15
    int l    = lane & 15;                    // feature quad (4 fp8)
    int node = blockIdx.x * 16 + nib;
    bool nv  = node < N;
    int nodec = nv ? node : N - 1;
    int start = row_ptr[nodec];
    int pdeg  = nv ? (row_ptr[nodec + 1] - start) : 0;   // padded degree (mult of 4)
    int md = pdeg;
#pragma unroll
    for (int off = 16; off <= 32; off <<= 1) md = max(md, __shfl_xor(md, off, 64));

    size_t base = (size_t)nodec * 16 + l;
    unsigned vself = hin[base];
    float d2       = dinv2[nodec];

    float s[4];
#pragma unroll
    for (int i = 0; i < 4; ++i) s[i] = 0.f;

    const unsigned* rp = ep + start;
    uint4 ea = *(const uint4*)rp;                               // slots 0..3
    uint4 eb = *(const uint4*)(rp + ((4 < pdeg) ? 4 : 0));      // slots 4..7
    for (int batch = 0; batch < md; batch += 8) {
        uint4 ca = ea, cb = eb;
        int n0 = batch + 8, n1 = batch + 12;
        ea = *(const uint4*)(rp + ((n0 < pdeg) ? n0 : 0));      // prefetch next step
        eb = *(const uint4*)(rp + ((n1 < pdeg) ? n1 : 0));
        unsigned v0 = hin[(size_t)(ca.x & 0xFFFFu) * 16 + l];
        unsigned v1 = hin[(size_t)(ca.y & 0xFFFFu) * 16 + l];
        unsigned v2 = hin[(size_t)(ca.z & 0xFFFFu) * 16 + l];
        unsigned v3 = hin[(size_t)(ca.w & 0xFFFFu) * 16 + l];
        unsigned v4 = hin[(size_t)(cb.x & 0xFFFFu) * 16 + l];
        unsigned v5 = hin[(size_t)(cb.y & 0xFFFFu) * 16 + l];
        unsigned v6 = hin[(size_t)(cb.z & 0xFFFFu) * 16 + l];
        unsigned v7 = hin[(size_t)(cb.w & 0xFFFFu) * 16 + l];
        accum4(s, v0, (batch     < pdeg) ? ep_w(ca.x) : 0.0f);
        accum4(s, v1, (batch + 1 < pdeg) ? ep_w(ca.y) : 0.0f);
        accum4(s, v2, (batch + 2 < pdeg) ? ep_w(ca.z) : 0.0f);
        accum4(s, v3, (batch + 3 < pdeg) ? ep_w(ca.w) : 0.0f);
        accum4(s, v4, (batch + 4 < pdeg) ? ep_w(cb.x) : 0.0f);
        accum4(s, v5, (batch + 5 < pdeg) ? ep_w(cb.y) : 0.0f);
        accum4(s, v6, (batch + 6 < pdeg) ? ep_w(cb.z) : 0.0f);
        accum4(s, v7, (batch + 7 < pdeg) ? ep_w(cb.w) : 0.0f);
    }
    if (nv) {
        accum4(s, vself, d2);                    // self-loop term (order preserved)
        if (WRITE_H) {
            hout[base] = pack_fp8x4(s[0], s[1], s[2], s[3]);
        }
        // NT-stream s as fp16 (no L2 pollution, no MSHR hold)
        __half2 h0 = __floats2half2_rn(s[0], s[1]);
        __half2 h1 = __floats2half2_rn(s[2], s[3]);
        unsigned long long acc64 =
            ((unsigned long long)(*(unsigned*)&h1) << 32) | (*(unsigned*)&h0);
        __builtin_nontemporal_store(acc64,
            (unsigned long long*)(haccl + (size_t)nodec * H + l * 4));
    }
}

// ---------------------------------------------------------------------------
// Final MLP: sum the 10 fp16 hop slices (coalesced stream), fuse
// h = relu(CK*acc + AL*y0 + b1); out = h @ W2 + b2.
// ---------------------------------------------------------------------------
constexpr int HSP = 68;
__global__ __launch_bounds__(256) void k_mlp(const __half* __restrict__ hacc,  // K x N x H
                                             const float4* __restrict__ y04,
                                             const float* __restrict__ b1,
                                             const float* __restrict__ W2,
                                             const float* __restrict__ b2,
                                             float* __restrict__ out) {
    __shared__ float w2s[H * C];
    __shared__ float hs[16 * HSP];
    __shared__ float b2s[C];
    __shared__ float b1s[H];
    int t = threadIdx.x;
    for (int i = t; i < H * C; i += 256) w2s[i] = W2[i];
    if (t < C) b2s[t] = b2[t];
    if (t < H) b1s[t] = b1[t];
    __syncthreads();
    int lane = t & 63;
    int nib  = (t >> 6) * 4 + (lane >> 4);   // node-in-block 0..15
    int l    = lane & 15;                    // feature quad
    int node = blockIdx.x * 16 + nib;
    if (node < N) {
        size_t off = (size_t)node * H + l * 4;
        float s[4] = {0.f, 0.f, 0.f, 0.f};
#pragma unroll
        for (int k = 0; k < K; ++k) {
            uint2 v = *(const uint2*)(hacc + (size_t)k * N * H + off);
            float2 f0 = __half22float2(*(__half2*)&v.x);
            float2 f1 = __half22float2(*(__half2*)&v.y);
            s[0] += f0.x; s[1] += f0.y; s[2] += f1.x; s[3] += f1.y;
        }
        float4 ya = y04[(size_t)node * (H / 4) + l];
        const float* bp = b1s + l * 4;
        float* hp = hs + nib * HSP + l * 4;
        hp[0] = fmaxf(fmaf(CK, s[0], fmaf(AL, ya.x, bp[0])), 0.f);
        hp[1] = fmaxf(fmaf(CK, s[1], fmaf(AL, ya.y, bp[1])), 0.f);
        hp[2] = fmaxf(fmaf(CK, s[2], fmaf(AL, ya.z, bp[2])), 0.f);
        hp[3] = fmaxf(fmaf(CK, s[3], fmaf(AL, ya.w, bp[3])), 0.f);
    }
    __syncthreads();
    int node0 = blockIdx.x * 16;
    for (int o = t; o < 16 * C; o += 256) {
        int nl = o / C, c = o % C;
        int n2 = node0 + nl;
        if (n2 >= N) continue;
        float v = b2s[c];
        const float* hr = &hs[nl * HSP];
#pragma unroll
        for (int k = 0; k < H; ++k) v = fmaf(hr[k], w2s[k * C + c], v);
        out[n2 * C + c] = v;
    }
}

// ---------------------------------------------------------------------------
extern "C" void kernel_launch(void* const* d_in, const int* in_sizes, int n_in,
                              void* d_out, int out_size, void* d_ws, size_t ws_size,
                              hipStream_t stream) {
    const float* x  = (const float*)d_in[0];
    const int*   ei = (const int*)d_in[1];
    const float* ew = (const float*)d_in[2];
    const float* W1 = (const float*)d_in[3];
    const float* b1 = (const float*)d_in[4];
    const float* W2 = (const float*)d_in[5];
    const float* b2 = (const float*)d_in[6];
    float* out = (float*)d_out;

    const int* row = ei;
    const int* col = ei + E;

    char* ws = (char*)d_ws;
    size_t off = 0;
    auto alloc = [&](size_t bytes) -> char* {
        char* p = ws + off;
        off = (off + bytes + 1023) & ~(size_t)1023;
        return p;
    };
    constexpr size_t EPAD = (size_t)E + 3 * (size_t)N + 1024;  // padded CSR capacity
    float*              y0    = (float*)alloc((size_t)N * H * 4);
    unsigned char*      y0f8  = (unsigned char*)alloc((size_t)N * H);
    unsigned char*      ha    = (unsigned char*)alloc((size_t)N * H);
    unsigned char*      hb    = (unsigned char*)alloc((size_t)N * H);
    __half*             hacc  = (__half*)alloc((size_t)K * N * H * 2);  // 64 MB, NT-written
    int*                cnt   = (int*)alloc((size_t)N * 4);       // fully written by k_cnt
    unsigned*           bhT   = (unsigned*)alloc((size_t)M * 4);  // fully written by k_hist
    unsigned*           bsumA = (unsigned*)alloc(512 * 4);
    unsigned long long* barr  = (unsigned long long*)alloc((size_t)E * 8);
    float*    dinv    = (float*)alloc((size_t)N * 4);
    float*    dinv2   = (float*)alloc((size_t)N * 4);
    int*      row_ptr = (int*)alloc((size_t)(N + 1) * 4);
    int*      bsum    = (int*)alloc(64 * 4);
    unsigned* ep      = (unsigned*)alloc(EPAD * 4);               // pads zeroed by k_addoff

    // 1) y0 = x @ W1 (fp32 + fp8)
    k_gemm1<<<(N + G1N - 1) / G1N, 256, 0, stream>>>(x, W1, y0, y0f8);

    // 2) atomic-free CSR build (LDS bucket sort by row>>6)
    k_hist  <<<HB, 256, 0, stream>>>(row, bhT);
    k_scan1 <<<SB, 1024, 0, stream>>>(bhT, bsumA);
    k_scan2 <<<1, 512, 0, stream>>>(bsumA);
    k_bucket<<<HB, 256, 0, stream>>>(row, col, ew, bhT, bsumA, barr);
    k_cnt   <<<NBIN, 256, 0, stream>>>(barr, bhT, bsumA, cnt);

    // 3) scan (padded degrees) -> row_ptr; fused bsum-prefix + pad zeroing
    k_scan_blocks<<<NB, 1024, 0, stream>>>(cnt, row_ptr, bsum);
    k_addoff<<<NB, 1024, 0, stream>>>(row_ptr, bsum, cnt, ep);

    // 4) emit CSR records + weighted degree/dinv (fused), then normalize
    k_emit<<<NBIN, 256, 0, stream>>>(barr, bhT, bsumA, row_ptr, ep, dinv, dinv2);
    k_norm<<<(N + 31) / 32, 256, 0, stream>>>(ep, row_ptr, dinv);

    // 5) K hops (each NT-streams its fp16 slice); then fused MLP over slices
    const unsigned* hin = (const unsigned*)y0f8;
    unsigned* bufs[2] = {(unsigned*)ha, (unsigned*)hb};
    const float4* y04 = (const float4*)y0;
    int grid = (N + 15) / 16;
    for (int hop = 0; hop < K; ++hop) {
        unsigned* hout = bufs[hop & 1];
        __half* haccl = hacc + (size_t)hop * N * H;
        if (hop < K - 1)
            k_prop<true><<<grid, 256, 0, stream>>>(hin, hout, haccl, dinv2, row_ptr, ep);
        else
            k_prop<false><<<grid, 256, 0, stream>>>(hin, hout, haccl, dinv2, row_ptr, ep);
        hin = hout;
    }
    k_mlp<<<grid, 256, 0, stream>>>(hacc, y04, b1, W2, b2, out);
}